// Round 4
// baseline (1482.867 us; speedup 1.0000x reference)
//
#include <hip/hip_runtime.h>
#include <math.h>

#define DEVFN static __device__ __forceinline__

static constexpr int BB = 8, VV = 13, HH = 32, WW = 64;
static constexpr int NPLANE = HH * WW;        // 2048
static constexpr int NF = BB * VV * NPLANE;   // 212992
static constexpr int NHB = BB * 65 * NPLANE;  // 1064960
static constexpr int GSZ = 512 * 256;         // mega grid threads

static constexpr float DT = 300.0f;
static constexpr float KHc = 15.0f, KVc = 0.1f;
static constexpr float OMEGAc = 7.29e-5f;
static constexpr float L_Vc = 2.5e6f;
static constexpr float R_GASc = 8.314f;
static constexpr float C_Pc = 1005.0f;
static constexpr float PTHc = 0.8f;
static constexpr float PYc  = (float)(3.14159265358979323846 * 6371000.0 / 33.0);
static constexpr float PXCc = (float)(2.0 * 3.14159265358979323846 * 6371000.0 / 64.0);
static constexpr float RCCc = (float)(0.7 * 5.67e-8 * 287.0 / (1005.0 * 100.0));
static constexpr float FBIG = 3.402823466e38f;

__constant__ float cDZ[13]  = {50,50,50,50,50,75,100,100,100,125,112,75,75};
__constant__ float cPRS[13] = {50,100,150,200,250,300,400,500,600,700,850,925,1000};

typedef short bf16x8 __attribute__((ext_vector_type(8)));
typedef float f32x4 __attribute__((ext_vector_type(4)));

DEVFN int pmh(int r){ return r < 0 ? r + 2 : (r > HH - 1 ? r - 2 : r); }
DEVFN int pmv(int r){ return r < 0 ? r + 2 : (r > VV - 1 ? r - 2 : r); }
DEVFN float latOf(int h){ return (90.0f - (float)(h + 1) * (180.0f / 33.0f)) * 0.017453292519943295f; }
DEVFN float avoid_inf(float t){
  if (t == 0.0f) t = 0.1f;
  if (fabsf(t) < 1.0f) t = copysignf(1.0f, t);
  return t;
}
DEVFN unsigned short f2bf(float f){
  unsigned u = __float_as_uint(f);
  unsigned r = (u + 0x7fffu + ((u >> 16) & 1u)) >> 16;
  return (unsigned short)r;
}

// ---- stencils on [B][13][32][64] ----
DEVFN float d_xf(const float* __restrict__ F, int rb, int w, float invpx){
  return (F[rb + ((w + 62) & 63)] - 8.f * F[rb + ((w + 63) & 63)]
        + 8.f * F[rb + ((w + 1) & 63)] - F[rb + ((w + 2) & 63)]) * (1.f / 12.f) * invpx;
}
DEVFN float d_yf(const float* __restrict__ F, int bvbase, int h, int w){
  return (-F[bvbase + pmh(h - 2) * 64 + w] + 8.f * F[bvbase + pmh(h - 1) * 64 + w]
          - 8.f * F[bvbase + pmh(h + 1) * 64 + w] + F[bvbase + pmh(h + 2) * 64 + w]) * (1.f / 12.f) * (1.f / PYc);
}
DEVFN float d_zf(const float* __restrict__ F, int bbase, int v, int hw){
  return (-F[bbase + pmv(v - 2) * 2048 + hw] + 8.f * F[bbase + pmv(v - 1) * 2048 + hw]
          - 8.f * F[bbase + pmv(v + 1) * 2048 + hw] + F[bbase + pmv(v + 2) * 2048 + hw]) * (1.f / 12.f) / cDZ[v];
}
DEVFN float dxxf(const float* __restrict__ F, int rb, int w, float invpx){
  float s = F[rb + ((w + 60) & 63)] - 16.f * F[rb + ((w + 61) & 63)] + 64.f * F[rb + ((w + 62) & 63)]
          + 16.f * F[rb + ((w + 63) & 63)] - 130.f * F[rb + w] + 16.f * F[rb + ((w + 1) & 63)]
          + 64.f * F[rb + ((w + 2) & 63)] - 16.f * F[rb + ((w + 3) & 63)] + F[rb + ((w + 4) & 63)];
  return s * (1.f / 144.f) * invpx * invpx;
}
DEVFN float dyyf(const float* __restrict__ F, int bvbase, int h, int w){
  float g0 = d_yf(F, bvbase, pmh(h - 2), w);
  float g1 = d_yf(F, bvbase, pmh(h - 1), w);
  float g2 = d_yf(F, bvbase, pmh(h + 1), w);
  float g3 = d_yf(F, bvbase, pmh(h + 2), w);
  return (-g0 + 8.f * g1 - 8.f * g2 + g3) * (1.f / 12.f) * (1.f / PYc);
}
DEVFN float dzzf(const float* __restrict__ F, int bbase, int v, int hw){
  float g0 = d_zf(F, bbase, pmv(v - 2), hw);
  float g1 = d_zf(F, bbase, pmv(v - 1), hw);
  float g2 = d_zf(F, bbase, pmv(v + 1), hw);
  float g3 = d_zf(F, bbase, pmv(v + 2), hw);
  return (-g0 + 8.f * g1 - 8.f * g2 + g3) * (1.f / 12.f) / cDZ[v];
}

// ---- reductions ----
DEVFN float waveRedSum(float v){ for (int o = 32; o; o >>= 1) v += __shfl_down(v, o, 64); return v; }
DEVFN float waveRedMin(float v){ for (int o = 32; o; o >>= 1) v = fminf(v, __shfl_down(v, o, 64)); return v; }
DEVFN float waveRedMax(float v){ for (int o = 32; o; o >>= 1) v = fmaxf(v, __shfl_down(v, o, 64)); return v; }

template<int OP, int NWV>
static __device__ float blockRedN(float v){
  __shared__ float s[NWV];
  v = OP == 0 ? waveRedSum(v) : OP == 1 ? waveRedMin(v) : waveRedMax(v);
  int lane = threadIdx.x & 63, wid = threadIdx.x >> 6;
  __syncthreads();
  if (lane == 0) s[wid] = v;
  __syncthreads();
  float r = s[0];
  #pragma unroll
  for (int k = 1; k < NWV; ++k)
    r = OP == 0 ? r + s[k] : OP == 1 ? fminf(r, s[k]) : fmaxf(r, s[k]);
  return r;
}

// ---- manual grid barrier (all blocks resident by construction) ----
DEVFN void gridBar(unsigned* cnt, unsigned* gen, unsigned nblk){
  __threadfence();
  __syncthreads();
  if (threadIdx.x == 0){
    unsigned g = __hip_atomic_load(gen, __ATOMIC_RELAXED, __HIP_MEMORY_SCOPE_AGENT);
    unsigned a = __hip_atomic_fetch_add(cnt, 1u, __ATOMIC_ACQ_REL, __HIP_MEMORY_SCOPE_AGENT);
    if (a == nblk - 1u){
      __hip_atomic_store(cnt, 0u, __ATOMIC_RELAXED, __HIP_MEMORY_SCOPE_AGENT);
      __hip_atomic_store(gen, g + 1u, __ATOMIC_RELEASE, __HIP_MEMORY_SCOPE_AGENT);
    } else {
      while (__hip_atomic_load(gen, __ATOMIC_ACQUIRE, __HIP_MEMORY_SCOPE_AGENT) == g)
        __builtin_amdgcn_s_sleep(8);
    }
  }
  __syncthreads();
  __threadfence();
}

// ================= launch 1: transpose x + pack both weights + zero sync =================
__global__ void __launch_bounds__(256) pre_k(const float* __restrict__ x,
    const float* __restrict__ w1, const float* __restrict__ w2,
    unsigned short* __restrict__ XT, unsigned short* __restrict__ wp1,
    unsigned short* __restrict__ wp2, unsigned* __restrict__ sync)
{
  int blk = blockIdx.x, t = threadIdx.x;
  if (blk == 0 && t < 8) sync[t] = 0u;
  if (blk < 1024){
    __shared__ float tile[16 * 68];
    int zz = blk >> 8, rem = blk & 255;
    int b = rem >> 5, h = rem & 31;
    for (int p = zz * 4; p < zz * 4 + 4; ++p){
      int cbase = p * 16;
      __syncthreads();
      {
        int cl = t >> 4, w4 = (t & 15) * 4;
        float4 v = *(const float4*)(x + (((size_t)(b * 256 + cbase + cl) * 32 + h) * 64 + w4));
        tile[cl * 68 + w4 + 0] = v.x; tile[cl * 68 + w4 + 1] = v.y;
        tile[cl * 68 + w4 + 2] = v.z; tile[cl * 68 + w4 + 3] = v.w;
      }
      __syncthreads();
      {
        int w = t >> 2, c4 = (t & 3) * 4;
        ushort4 o;
        o.x = f2bf(tile[(c4 + 0) * 68 + w]);
        o.y = f2bf(tile[(c4 + 1) * 68 + w]);
        o.z = f2bf(tile[(c4 + 2) * 68 + w]);
        o.w = f2bf(tile[(c4 + 3) * 68 + w]);
        *(ushort4*)(XT + (((size_t)(b * 32 + h) * 64 + w) * 256 + cbase + c4)) = o;
      }
    }
  } else {
    const int T1 = 9 * 80 * 256;
    const int T2 = 9 * 256 * 96;
    int idx = (blk - 1024) * 256 + t;
    if (idx < T1){
      int dir = idx / (80 * 256);
      int r = idx - dir * (80 * 256);
      int co = r / 256, ci = r - co * 256;
      float v = (co < 65) ? w1[((size_t)(co * 256 + ci)) * 9 + dir] : 0.f;
      wp1[idx] = f2bf(v);
    } else if (idx < T1 + T2){
      int j = idx - T1;
      int dir = j / (256 * 96);
      int r = j - dir * (256 * 96);
      int co = r / 96, ci = r - co * 96;
      float v = (ci < 65) ? w2[((size_t)(co * 65 + ci)) * 9 + dir] : 0.f;
      wp2[j] = f2bf(v);
    }
  }
}

// ================= conv1 via MFMA (unchanged) =================
template<int CIT, int CIL, int CO, int COp, int NW, int MF, int SWZ>
__global__ void __launch_bounds__(NW * 64) conv_mfma_k(
    const unsigned short* __restrict__ XT, const unsigned short* __restrict__ Wp,
    const float* __restrict__ bias, float* __restrict__ out)
{
  __shared__ __align__(16) unsigned short Xl[3 * 66 * CIL];
  const int C8 = CIL / 8;
  int tid = threadIdx.x;
  int h = blockIdx.x, b = blockIdx.y;
  int wid = tid >> 6, lane = tid & 63;
  int l15 = lane & 15, q = lane >> 4;

  f32x4 acc[MF][4];
  #pragma unroll
  for (int mf = 0; mf < MF; ++mf)
    #pragma unroll
    for (int nf = 0; nf < 4; ++nf){ f32x4 z = {0.f, 0.f, 0.f, 0.f}; acc[mf][nf] = z; }

  for (int cp = 0; cp < CIT / CIL; ++cp){
    if (cp) __syncthreads();
    for (int idx = tid; idx < 3 * 64 * C8; idx += NW * 64){
      int r = idx / (64 * C8);
      int rest = idx - r * 64 * C8;
      int j1 = rest / C8;
      int c8 = rest - j1 * C8;
      int j = j1 + 1;
      int hh = h + r - 1;
      uint4 val = make_uint4(0, 0, 0, 0);
      if (hh >= 0 && hh < 32)
        val = *(const uint4*)(XT + (((size_t)(b * 32 + hh) * 64 + j1) * CIT + cp * CIL + c8 * 8));
      int dst = (r * 66 + j) * CIL + ((c8 * 8) ^ ((j & SWZ) << 3));
      *(uint4*)(Xl + dst) = val;
    }
    for (int idx = tid; idx < 3 * 2 * C8; idx += NW * 64){
      int r = idx / (2 * C8);
      int rest = idx - r * 2 * C8;
      int js = rest / C8;
      int c8 = rest - js * C8;
      int j = js ? 65 : 0;
      int dst = (r * 66 + j) * CIL + ((c8 * 8) ^ ((j & SWZ) << 3));
      *(uint4*)(Xl + dst) = make_uint4(0, 0, 0, 0);
    }
    __syncthreads();

    for (int dir = 0; dir < 9; ++dir){
      int dy = dir / 3, dx = dir - dy * 3;
      #pragma unroll
      for (int kc = 0; kc < CIL / 32; ++kc){
        int kb = kc * 32 + q * 8;
        bf16x8 a[MF];
        #pragma unroll
        for (int mf = 0; mf < MF; ++mf){
          int co = wid * (MF * 16) + mf * 16 + l15;
          a[mf] = *(const bf16x8*)(Wp + ((size_t)(dir * COp + co) * CIT + cp * CIL + kb));
        }
        #pragma unroll
        for (int nf = 0; nf < 4; ++nf){
          int j = nf * 16 + l15 + dx;
          bf16x8 bfrag = *(const bf16x8*)(Xl + ((dy * 66 + j) * CIL + (kb ^ ((j & SWZ) << 3))));
          #pragma unroll
          for (int mf = 0; mf < MF; ++mf)
            acc[mf][nf] = __builtin_amdgcn_mfma_f32_16x16x32_bf16(a[mf], bfrag, acc[mf][nf], 0, 0, 0);
        }
      }
    }
  }
  #pragma unroll
  for (int mf = 0; mf < MF; ++mf){
    #pragma unroll
    for (int r = 0; r < 4; ++r){
      int co = wid * (MF * 16) + mf * 16 + q * 4 + r;
      if (CO != COp && co >= CO) continue;
      float bv = bias[co];
      #pragma unroll
      for (int nf = 0; nf < 4; ++nf){
        int pix = nf * 16 + l15;
        out[(size_t)(b * CO + co) * 2048 + h * 64 + pix] = acc[mf][nf][r] + bv;
      }
    }
  }
}

// ================= mega kernel =================
struct GB { const float* g[5]; const float* b[5]; };

struct MegaArgs {
  const float* hb; const float* coef;
  GB gb;
  float *Fz, *Fq, *Fu, *Fvf, *Ft;
  float *zx, *zy, *zz, *ux, *vy, *wv;
  float *C0, *prr;
  float *Ua, *Ub, *Va, *Vb, *Ta, *Tb;
  float *duA, *dvA, *dtA, *k4t, *ztA, *qtA;
  float *bnp, *partS, *sc1g;
  float *pduv, *pdt, *pqt, *pzt;
  float *mid;
  unsigned short* MT;
  unsigned* sync;
};

template<int STAGE>
DEVFN void stageBody(int blk, int t,
  const float* __restrict__ U, const float* __restrict__ Vf, const float* __restrict__ T,
  const MegaArgs& a, float ss, float off,
  float* __restrict__ Uo, float* __restrict__ Vo, float* __restrict__ To, float cnext)
{
  int gtid = blk * 256 + t;
  float aumn = FBIG, aumx = -FBIG, avmn = FBIG, avmx = -FBIG, atmn = FBIG, atmx = -FBIG;
  float qmn = FBIG, qmx = -FBIG;
  #pragma unroll 1
  for (int i = gtid; i < NF; i += GSZ){
    int w = i & 63, h = (i >> 6) & 31;
    int bv = i >> 11;
    int v = bv % 13;
    int bvbase = bv * 2048;
    int rb = bvbase + h * 64;
    int bbase = (bv - v) * 2048;
    int hw = h * 64 + w;
    float lat = latOf(h);
    float invpx = 1.0f / (PXCc * cosf(lat));
    float fcor = 2.0f * OMEGAc * sinf(lat);
    float wvi = a.wv[i];
    float Ui = U[i], Vi = Vf[i], Ti = T[i];
    float Fui = (STAGE == 1) ? Ui : a.Fu[i];
    float Fvi = (STAGE == 1) ? Vi : a.Fvf[i];

    float dyU = d_yf(U, bvbase, h, w);
    float dzU = d_zf(U, bbase, v, hw);
    float dxV = d_xf(Vf, rb, w, invpx);
    float dzV = d_zf(Vf, bbase, v, hw);
    float mixU = KHc * (dxxf(U, rb, w, invpx) + dyyf(U, bvbase, h, w)) + KVc * dzzf(U, bbase, v, hw);
    float mixV = KHc * (dxxf(Vf, rb, w, invpx) + dyyf(Vf, bvbase, h, w)) + KVc * dzzf(Vf, bbase, v, hw);
    float ku = -Ui * a.ux[i] - Vi * dyU - wvi * dzU + fcor * Vi - a.zx[i] + mixU;
    float kv = -Ui * dxV - Vi * a.vy[i] - wvi * dzV - fcor * Ui - a.zy[i] + mixV;

    float C0i;
    if (STAGE == 1){
      float zzi = a.zz[i], qi = a.Fq[i];
      float rho = -1.0f / avoid_inf(zzi);
      float p = rho * R_GASc * Ti;
      float tcc = Ti - 273.15f;
      float arg = 17.67f * tcc / avoid_inf(tcc + 243.5f);
      float es = 6.112f * expf(arg * ss + off) * 100.0f;
      float qs = fmaxf(0.622f * es / avoid_inf(p - 0.378f * es), 1e-6f);
      float rh = qi / avoid_inf(qs);
      float rate = (rh > PTHc) ? (qi - PTHc * qs) * (1.0f / DT) : 0.0f;
      a.prr[i] = rate;
      C0i = -(L_Vc + 1.0f) * zzi * wvi * (1.0f / C_Pc) + rate * (L_Vc / C_Pc);
      a.C0[i] = C0i;
    } else {
      C0i = a.C0[i];
    }

    float dxT = d_xf(T, rb, w, invpx);
    float dyT = d_yf(T, bvbase, h, w);
    float dzT = d_zf(T, bbase, v, hw);
    float mixT = KHc * (dxxf(T, rb, w, invpx) + dyyf(T, bvbase, h, w)) + KVc * dzzf(T, bbase, v, hw);
    float ta = Ti + 273.15f;
    float t2 = ta * ta;
    float ta5 = t2 * t2 * ta;
    float rc = -RCCc * ta5 / cPRS[v];
    float kt = C0i - Fui * dxT - Fvi * dyT - wvi * dzT + mixT + rc;

    if (STAGE == 1){ a.duA[i] = ku; a.dvA[i] = kv; a.dtA[i] = kt; }
    else if (STAGE < 4){ a.duA[i] += 2.f * ku; a.dvA[i] += 2.f * kv; a.dtA[i] += 2.f * kt; }
    else {
      float au = a.duA[i] + ku, av = a.dvA[i] + kv, at = a.dtA[i] + kt;
      a.duA[i] = au; a.dvA[i] = av; a.dtA[i] = at; a.k4t[i] = kt;
      aumn = fminf(aumn, au); aumx = fmaxf(aumx, au);
      avmn = fminf(avmn, av); avmx = fmaxf(avmx, av);
      atmn = fminf(atmn, at); atmx = fmaxf(atmx, at);
    }
    if (STAGE < 4){
      float Fti = (STAGE == 1) ? Ti : a.Ft[i];
      Uo[i] = Fui + cnext * ku;
      Vo[i] = Fvi + cnext * kv;
      To[i] = Fti + cnext * kt;
    }
    if (STAGE == 2){
      float qtv = -Fui * d_xf(a.Fq, rb, w, invpx) - Fvi * d_yf(a.Fq, bvbase, h, w) - wvi * d_zf(a.Fq, bbase, v, hw)
                + KHc * (dxxf(a.Fq, rb, w, invpx) + dyyf(a.Fq, bvbase, h, w)) + KVc * dzzf(a.Fq, bbase, v, hw) - a.prr[i];
      a.qtA[i] = qtv;
      qmn = fminf(qmn, qtv); qmx = fmaxf(qmx, qtv);
    }
  }
  if (STAGE == 4){
    float m0 = blockRedN<1,4>(aumn), m1 = blockRedN<2,4>(aumx);
    float m2 = blockRedN<1,4>(avmn), m3 = blockRedN<2,4>(avmx);
    float m4 = blockRedN<1,4>(atmn), m5 = blockRedN<2,4>(atmx);
    if (!t){
      float* pp = a.pduv + blk * 4;
      pp[0] = m0; pp[1] = m1; pp[2] = m2; pp[3] = m3;
      a.pdt[blk * 2] = m4; a.pdt[blk * 2 + 1] = m5;
    }
  }
  if (STAGE == 2){
    float m0 = blockRedN<1,4>(qmn), m1 = blockRedN<2,4>(qmx);
    if (!t){ a.pqt[blk * 2] = m0; a.pqt[blk * 2 + 1] = m1; }
  }
}

__global__ void __launch_bounds__(256, 2) mega_k(MegaArgs a)
{
  __shared__ float As[65], Bs[65];
  __shared__ float tileS[16 * 68];
  int blk = blockIdx.x, t = threadIdx.x;
  int gtid = blk * 256 + t;
  unsigned* cnt = a.sync;
  unsigned* gen = a.sync + 1;

  // ---- P0: BN1 partial sums (per (channel, batch) slice) ----
  #pragma unroll 1
  for (int rep = 0; rep < 2; ++rep){
    int idx = blk + rep * 512;
    if (idx < 520){
      int c = idx % 65, bb = idx / 65;
      const float* src = a.hb + (size_t)(bb * 65 + c) * 2048;
      float s = 0.f, s2 = 0.f;
      for (int j = t; j < 2048; j += 256){ float v = src[j]; s += v; s2 += v * v; }
      s = blockRedN<0,4>(s); s2 = blockRedN<0,4>(s2);
      if (!t){ a.bnp[idx * 2] = s; a.bnp[idx * 2 + 1] = s2; }
    }
  }
  gridBar(cnt, gen, 512);

  // ---- P1: prep (part-per-field, all 512 blocks) ----
  {
    if (t < 65){
      float s = 0.f, s2 = 0.f;
      for (int bb = 0; bb < 8; ++bb){ int idx = t + 65 * bb; s += a.bnp[idx * 2]; s2 += a.bnp[idx * 2 + 1]; }
      float m = s * (1.f / 16384.f);
      float var = s2 * (1.f / 16384.f) - m * m;
      float rstd = rsqrtf(var + 1e-5f);
      int f = t / 13, k = t - f * 13;
      float g = a.gb.g[f][k], bbv = a.gb.b[f][k];
      As[t] = g * rstd; Bs[t] = bbv - m * g * rstd;
    }
    __syncthreads();
    int part = blk >> 6;
    int col = ((blk & 63) << 8) | t;
    int b = col >> 11, p = col & 2047, h = p >> 6, w = p & 63;
    int hbase = b * 65 * NPLANE;
    auto hn = [&](int ch, int hh, int ww)->float {
      return a.hb[hbase + ch * 2048 + hh * 64 + ww] * As[ch] + Bs[ch];
    };
    int fb = (b * 13) * 2048 + p;
    float lat = latOf(h);
    float invpx = 1.0f / (PXCc * cosf(lat));
    int wm2 = (w + 62) & 63, wm1 = (w + 63) & 63, wp1 = (w + 1) & 63, wp2v = (w + 2) & 63;
    int hm2 = pmh(h - 2), hm1 = pmh(h - 1), hp1 = pmh(h + 1), hp2 = pmh(h + 2);
    float fmn = FBIG, fmx = -FBIG, fsm = 0.f, smn = FBIG, smx = -FBIG;
    if (part < 5){
      int ch0 = part * 13;
      float c[13];
      #pragma unroll
      for (int v = 0; v < 13; ++v) c[v] = hn(ch0 + v, h, w);
      float* Fdst = part == 0 ? a.Fz : part == 1 ? a.Fq : part == 2 ? a.Fu : part == 3 ? a.Fvf : a.Ft;
      #pragma unroll
      for (int v = 0; v < 13; ++v) Fdst[fb + v * 2048] = c[v];
      if (part == 0){
        #pragma unroll
        for (int v = 0; v < 13; ++v){
          a.zz[fb + v * 2048] = (-c[pmv(v - 2)] + 8.f * c[pmv(v - 1)] - 8.f * c[pmv(v + 1)] + c[pmv(v + 2)]) * (1.f / 12.f) / cDZ[v];
          float zxv = (hn(v, h, wm2) - 8.f * hn(v, h, wm1) + 8.f * hn(v, h, wp1) - hn(v, h, wp2v)) * (1.f / 12.f) * invpx;
          float zyv = (-hn(v, hm2, w) + 8.f * hn(v, hm1, w) - 8.f * hn(v, hp1, w) + hn(v, hp2, w)) * (1.f / 12.f) * (1.f / PYc);
          a.zx[fb + v * 2048] = zxv; a.zy[fb + v * 2048] = zyv;
        }
      }
      if (part == 2){
        #pragma unroll
        for (int v = 0; v < 13; ++v){
          float uxv = (hn(26 + v, h, wm2) - 8.f * hn(26 + v, h, wm1) + 8.f * hn(26 + v, h, wp1) - hn(26 + v, h, wp2v)) * (1.f / 12.f) * invpx;
          a.ux[fb + v * 2048] = uxv;
        }
      }
      if (part == 3){
        #pragma unroll
        for (int v = 0; v < 13; ++v){
          float vyv = (-hn(39 + v, hm2, w) + 8.f * hn(39 + v, hm1, w) - 8.f * hn(39 + v, hp1, w) + hn(39 + v, hp2, w)) * (1.f / 12.f) * (1.f / PYc);
          a.vy[fb + v * 2048] = vyv;
        }
      }
      if (part == 4){
        #pragma unroll
        for (int v = 0; v < 13; ++v){
          float tcc = c[v] - 273.15f;
          float arg = 17.67f * tcc / avoid_inf(tcc + 243.5f);
          smn = fminf(smn, arg); smx = fmaxf(smx, arg);
        }
      }
      #pragma unroll
      for (int v = 0; v < 13; ++v){ fmn = fminf(fmn, c[v]); fmx = fmaxf(fmx, c[v]); fsm += c[v]; }
    } else if (part == 5){
      float cum = 0.f;
      #pragma unroll
      for (int v = 0; v < 13; ++v){
        float uxv = (hn(26 + v, h, wm2) - 8.f * hn(26 + v, h, wm1) + 8.f * hn(26 + v, h, wp1) - hn(26 + v, h, wp2v)) * (1.f / 12.f) * invpx;
        float vyv = (-hn(39 + v, hm2, w) + 8.f * hn(39 + v, hm1, w) - 8.f * hn(39 + v, hp1, w) + hn(39 + v, hp2, w)) * (1.f / 12.f) * (1.f / PYc);
        cum += cDZ[v] * (uxv + vyv);
        a.wv[fb + v * 2048] = -cum;
      }
    }
    float* pb = a.partS + blk * 17;
    float r;
    r = blockRedN<1,4>(smn); if (!t) pb[0] = r;
    r = blockRedN<2,4>(smx); if (!t) pb[1] = r;
    #pragma unroll
    for (int f = 0; f < 5; ++f){
      r = blockRedN<1,4>(part == f ? fmn : FBIG);  if (!t) pb[2 + f * 3] = r;
      r = blockRedN<2,4>(part == f ? fmx : -FBIG); if (!t) pb[3 + f * 3] = r;
      r = blockRedN<0,4>(part == f ? fsm : 0.f);   if (!t) pb[4 + f * 3] = r;
    }
  }
  gridBar(cnt, gen, 512);

  // ---- P2: redundant sc1 reduce + RK stage 1 ----
  float ss, off;
  {
    float smn = FBIG, smx = -FBIG;
    float fmn[5] = {FBIG, FBIG, FBIG, FBIG, FBIG};
    float fmx[5] = {-FBIG, -FBIG, -FBIG, -FBIG, -FBIG};
    float fsm[5] = {0.f, 0.f, 0.f, 0.f, 0.f};
    #pragma unroll 1
    for (int r0 = t; r0 < 512; r0 += 256){
      const float* pr = a.partS + r0 * 17;
      smn = fminf(smn, pr[0]); smx = fmaxf(smx, pr[1]);
      #pragma unroll
      for (int f = 0; f < 5; ++f){
        fmn[f] = fminf(fmn[f], pr[2 + f * 3]);
        fmx[f] = fmaxf(fmx[f], pr[3 + f * 3]);
        fsm[f] += pr[4 + f * 3];
      }
    }
    smn = blockRedN<1,4>(smn); smx = blockRedN<2,4>(smx);
    #pragma unroll
    for (int f = 0; f < 5; ++f){
      fmn[f] = blockRedN<1,4>(fmn[f]);
      fmx[f] = blockRedN<2,4>(fmx[f]);
      fsm[f] = blockRedN<0,4>(fsm[f]);
    }
    ss = (3.01f + 3.47f) / (smx - smn);
    off = -3.47f - smn * ss;
    if (blk == 0 && t == 0){
      a.sc1g[0] = ss; a.sc1g[1] = off;
      #pragma unroll
      for (int f = 0; f < 5; ++f){
        a.sc1g[2 + f * 3] = fmn[f];
        a.sc1g[3 + f * 3] = fsm[f] * (1.0f / (float)NF);
        a.sc1g[4 + f * 3] = fmx[f];
      }
    }
  }
  stageBody<1>(blk, t, a.Fu, a.Fvf, a.Ft, a, ss, off, a.Ua, a.Va, a.Ta, 0.5f * DT);
  gridBar(cnt, gen, 512);
  stageBody<2>(blk, t, a.Ua, a.Va, a.Ta, a, ss, off, a.Ub, a.Vb, a.Tb, 0.5f * DT);
  gridBar(cnt, gen, 512);
  stageBody<3>(blk, t, a.Ub, a.Vb, a.Tb, a, ss, off, a.Ua, a.Va, a.Ta, DT);
  gridBar(cnt, gen, 512);
  stageBody<4>(blk, t, a.Ua, a.Va, a.Ta, a, ss, off, (float*)0, (float*)0, (float*)0, 0.f);
  gridBar(cnt, gen, 512);

  // ---- P6: z-tendency integral ----
  if (blk < 64){
    int col = blk * 256 + t;
    int b = col >> 11, p = col & 2047;
    int fb = b * 13 * 2048 + p;
    float cum = 0.f, mn = FBIG, mx = -FBIG;
    #pragma unroll
    for (int v = 0; v < 13; ++v){
      cum += cDZ[v] * (-R_GASc / cPRS[v]) * a.k4t[fb + v * 2048];
      a.ztA[fb + v * 2048] = cum;
      mn = fminf(mn, cum); mx = fmaxf(mx, cum);
    }
    mn = blockRedN<1,4>(mn); mx = blockRedN<2,4>(mx);
    if (!t){ a.pzt[blk * 2] = mn; a.pzt[blk * 2 + 1] = mx; }
  }
  gridBar(cnt, gen, 512);

  // ---- P7: redundant sc2 reduce + outmid ----
  {
    float dumn = FBIG, dumx = -FBIG, dvmn = FBIG, dvmx = -FBIG, dtmn2 = FBIG, dtmx2 = -FBIG;
    float qmn = FBIG, qmx = -FBIG;
    #pragma unroll 1
    for (int r0 = t; r0 < 512; r0 += 256){
      dumn = fminf(dumn, a.pduv[r0 * 4]);     dumx = fmaxf(dumx, a.pduv[r0 * 4 + 1]);
      dvmn = fminf(dvmn, a.pduv[r0 * 4 + 2]); dvmx = fmaxf(dvmx, a.pduv[r0 * 4 + 3]);
      dtmn2 = fminf(dtmn2, a.pdt[r0 * 2]);    dtmx2 = fmaxf(dtmx2, a.pdt[r0 * 2 + 1]);
      qmn = fminf(qmn, a.pqt[r0 * 2]);        qmx = fmaxf(qmx, a.pqt[r0 * 2 + 1]);
    }
    float zmn = (t < 64) ? a.pzt[t * 2] : FBIG;
    float zmx = (t < 64) ? a.pzt[t * 2 + 1] : -FBIG;
    dumn = blockRedN<1,4>(dumn); dumx = blockRedN<2,4>(dumx);
    dvmn = blockRedN<1,4>(dvmn); dvmx = blockRedN<2,4>(dvmx);
    dtmn2 = blockRedN<1,4>(dtmn2); dtmx2 = blockRedN<2,4>(dtmx2);
    qmn = blockRedN<1,4>(qmn);   qmx = blockRedN<2,4>(qmx);
    zmn = blockRedN<1,4>(zmn);   zmx = blockRedN<2,4>(zmx);

    float scz, ofz, scq, ofq, scu, ofu, scv, ofv, sct, oft;
    #define SC2C(F, RMN, RMX, CF, SCV, OFV) { \
      float mnf = a.sc1g[2 + F * 3], mef = a.sc1g[3 + F * 3], mxf = a.sc1g[4 + F * 3]; \
      float aa = (mnf - mef) * 0.05f, b2 = (mxf - mef) * 0.05f; \
      float dmn = RMN * CF, dmx = RMX * CF; \
      float s = (b2 - aa) / (dmx - dmn); \
      SCV = s * CF; OFV = aa - dmn * s; }
    SC2C(0, zmn, zmx, DT, scz, ofz)
    SC2C(1, qmn, qmx, DT, scq, ofq)
    SC2C(2, dumn, dumx, (DT / 6.f), scu, ofu)
    SC2C(3, dvmn, dvmx, (DT / 6.f), scv, ofv)
    SC2C(4, dtmn2, dtmx2, (DT / 6.f), sct, oft)
    #undef SC2C

    #pragma unroll 1
    for (int e = gtid; e < NHB; e += GSZ){
      int b = e / (65 * 2048);
      int r = e - b * 65 * 2048;
      int c = r >> 11, p = r & 2047;
      int f = c / 13, v = c - f * 13;
      int fi = (b * 13 + v) * 2048 + p;
      const float *Fp, *Rp; float sc_, of_;
      switch (f){
        case 0: Fp = a.Fz;  Rp = a.ztA; sc_ = scz; of_ = ofz; break;
        case 1: Fp = a.Fq;  Rp = a.qtA; sc_ = scq; of_ = ofq; break;
        case 2: Fp = a.Fu;  Rp = a.duA; sc_ = scu; of_ = ofu; break;
        case 3: Fp = a.Fvf; Rp = a.dvA; sc_ = scv; of_ = ofv; break;
        default: Fp = a.Ft; Rp = a.dtA; sc_ = sct; of_ = oft; break;
      }
      float phys = Fp[fi] + Rp[fi] * sc_ + of_;
      float cf = a.coef[c * 2048 + p];
      a.mid[e] = cf * phys + (1.0f - cf) * a.hb[e];
    }
  }
  gridBar(cnt, gen, 512);

  // ---- P8: transpose mid -> MT (bf16, CIT=96) ----
  if (blk < 256){
    int b = blk >> 5, h = blk & 31;
    #pragma unroll 1
    for (int ph = 0; ph < 6; ++ph){
      int cbase = ph * 16;
      __syncthreads();
      {
        int cl = t >> 4, w4 = (t & 15) * 4;
        int ci = cbase + cl;
        float4 v = make_float4(0.f, 0.f, 0.f, 0.f);
        if (ci < 65) v = *(const float4*)(a.mid + (((size_t)(b * 65 + ci) * 32 + h) * 64 + w4));
        tileS[cl * 68 + w4 + 0] = v.x; tileS[cl * 68 + w4 + 1] = v.y;
        tileS[cl * 68 + w4 + 2] = v.z; tileS[cl * 68 + w4 + 3] = v.w;
      }
      __syncthreads();
      {
        int w = t >> 2, c4 = (t & 3) * 4;
        ushort4 o;
        o.x = f2bf(tileS[(c4 + 0) * 68 + w]);
        o.y = f2bf(tileS[(c4 + 1) * 68 + w]);
        o.z = f2bf(tileS[(c4 + 2) * 68 + w]);
        o.w = f2bf(tileS[(c4 + 3) * 68 + w]);
        *(ushort4*)(a.MT + (((size_t)(b * 32 + h) * 64 + w) * 96 + cbase + c4)) = o;
      }
    }
  }
}

// ================= tail: conv2 + BN2 + residual =================
struct TailArgs {
  const unsigned short* MT; const unsigned short* Wp2; const float* bias;
  float* yout; const float* x; const float* gblk; const float* bblk;
  float* A2; float* B2; unsigned* sync;
};

__global__ void __launch_bounds__(512, 2) tail_k(TailArgs a)
{
  constexpr int CIL = 96, SWZ = 3, NW = 8, MF = 2;
  __shared__ __align__(16) unsigned short Xl[3 * 66 * CIL];
  const int C8 = CIL / 8;
  int tid = threadIdx.x;
  int blk = blockIdx.x;
  unsigned* cnt = a.sync;
  unsigned* gen = a.sync + 1;

  // ---- conv2 ----
  {
    int h = blk & 31, b = blk >> 5;
    int wid = tid >> 6, lane = tid & 63;
    int l15 = lane & 15, q = lane >> 4;
    f32x4 acc[MF][4];
    #pragma unroll
    for (int mf = 0; mf < MF; ++mf)
      #pragma unroll
      for (int nf = 0; nf < 4; ++nf){ f32x4 z = {0.f, 0.f, 0.f, 0.f}; acc[mf][nf] = z; }

    for (int idx = tid; idx < 3 * 64 * C8; idx += NW * 64){
      int r = idx / (64 * C8);
      int rest = idx - r * 64 * C8;
      int j1 = rest / C8;
      int c8 = rest - j1 * C8;
      int j = j1 + 1;
      int hh = h + r - 1;
      uint4 val = make_uint4(0, 0, 0, 0);
      if (hh >= 0 && hh < 32)
        val = *(const uint4*)(a.MT + (((size_t)(b * 32 + hh) * 64 + j1) * 96 + c8 * 8));
      int dst = (r * 66 + j) * CIL + ((c8 * 8) ^ ((j & SWZ) << 3));
      *(uint4*)(Xl + dst) = val;
    }
    for (int idx = tid; idx < 3 * 2 * C8; idx += NW * 64){
      int r = idx / (2 * C8);
      int rest = idx - r * 2 * C8;
      int js = rest / C8;
      int c8 = rest - js * C8;
      int j = js ? 65 : 0;
      int dst = (r * 66 + j) * CIL + ((c8 * 8) ^ ((j & SWZ) << 3));
      *(uint4*)(Xl + dst) = make_uint4(0, 0, 0, 0);
    }
    __syncthreads();

    for (int dir = 0; dir < 9; ++dir){
      int dy = dir / 3, dx = dir - dy * 3;
      #pragma unroll
      for (int kc = 0; kc < CIL / 32; ++kc){
        int kb = kc * 32 + q * 8;
        bf16x8 afr[MF];
        #pragma unroll
        for (int mf = 0; mf < MF; ++mf){
          int co = wid * (MF * 16) + mf * 16 + l15;
          afr[mf] = *(const bf16x8*)(a.Wp2 + ((size_t)(dir * 256 + co) * 96 + kb));
        }
        #pragma unroll
        for (int nf = 0; nf < 4; ++nf){
          int j = nf * 16 + l15 + dx;
          bf16x8 bfrag = *(const bf16x8*)(Xl + ((dy * 66 + j) * CIL + (kb ^ ((j & SWZ) << 3))));
          #pragma unroll
          for (int mf = 0; mf < MF; ++mf)
            acc[mf][nf] = __builtin_amdgcn_mfma_f32_16x16x32_bf16(afr[mf], bfrag, acc[mf][nf], 0, 0, 0);
        }
      }
    }
    #pragma unroll
    for (int mf = 0; mf < MF; ++mf){
      #pragma unroll
      for (int r = 0; r < 4; ++r){
        int co = wid * (MF * 16) + mf * 16 + q * 4 + r;
        float bv = a.bias[co];
        #pragma unroll
        for (int nf = 0; nf < 4; ++nf){
          int pix = nf * 16 + l15;
          a.yout[(size_t)(b * 256 + co) * 2048 + h * 64 + pix] = acc[mf][nf][r] + bv;
        }
      }
    }
  }
  gridBar(cnt, gen, 256);

  // ---- BN2 stats (block = channel) ----
  {
    int c = blk;
    float s = 0.f, s2 = 0.f;
    for (int j = tid; j < 16384; j += 512){
      int b = j >> 11, p = j & 2047;
      float v = a.yout[(size_t)(b * 256 + c) * 2048 + p];
      s += v; s2 += v * v;
    }
    s = blockRedN<0,8>(s); s2 = blockRedN<0,8>(s2);
    if (!tid){
      float m = s * (1.0f / 16384.0f);
      float var = s2 * (1.0f / 16384.0f) - m * m;
      float rstd = rsqrtf(var + 1e-5f);
      a.A2[c] = a.gblk[c] * rstd; a.B2[c] = a.bblk[c] - m * a.gblk[c] * rstd;
    }
  }
  gridBar(cnt, gen, 256);

  // ---- apply BN + residual ----
  {
    int gtid = blk * 512 + tid;
    #pragma unroll 1
    for (int e4 = gtid; e4 < 1048576; e4 += 131072){
      int c = (e4 >> 9) & 255;
      float4 v = ((const float4*)a.yout)[e4];
      float4 xv = ((const float4*)a.x)[e4];
      float aa = a.A2[c], bb = a.B2[c];
      v.x = v.x * aa + bb + xv.x;
      v.y = v.y * aa + bb + xv.y;
      v.z = v.z * aa + bb + xv.z;
      v.w = v.w * aa + bb + xv.w;
      ((float4*)a.yout)[e4] = v;
    }
  }
}

extern "C" void kernel_launch(void* const* d_in, const int* in_sizes, int n_in,
                              void* d_out, int out_size, void* d_ws, size_t ws_size,
                              hipStream_t stream)
{
  (void)in_sizes; (void)n_in; (void)out_size; (void)ws_size;
  const float* x        = (const float*)d_in[0];
  const float* w_norm   = (const float*)d_in[1];
  const float* b_norm   = (const float*)d_in[2];
  const float* w_innorm = (const float*)d_in[3];
  const float* b_innorm = (const float*)d_in[4];
  const float* coef     = (const float*)d_in[5];
  GB gb;
  for (int f = 0; f < 5; ++f){
    gb.g[f] = (const float*)d_in[6 + 2 * f];
    gb.b[f] = (const float*)d_in[7 + 2 * f];
  }
  const float* gblk = (const float*)d_in[16];
  const float* bblk = (const float*)d_in[17];
  float* yout = (float*)d_out;

  float* ws = (float*)d_ws;
  size_t off = 0;
  auto alloc = [&](size_t n){ float* p = ws + off; off += n; return p; };
  float* hb  = alloc(NHB);
  float* Fz  = alloc(NF); float* Fq  = alloc(NF); float* Fu  = alloc(NF);
  float* Fvf = alloc(NF); float* Ft  = alloc(NF);
  float* zx  = alloc(NF); float* zy  = alloc(NF); float* zz  = alloc(NF);
  float* ux  = alloc(NF); float* vy  = alloc(NF); float* wvel = alloc(NF);
  float* C0  = alloc(NF); float* prr = alloc(NF);
  float* Ua  = alloc(NF); float* Ub  = alloc(NF); float* Va  = alloc(NF); float* Vb = alloc(NF);
  float* Ta  = alloc(NF); float* Tb  = alloc(NF);
  float* duA = alloc(NF); float* dvA = alloc(NF); float* dtA = alloc(NF);
  float* k4t = alloc(NF); float* ztA = alloc(NF); float* qtA = alloc(NF);
  float* A2 = alloc(256); float* B2 = alloc(256);
  float* sc1g = alloc(32);
  float* bnp = alloc(1040);
  float* partS = alloc(512 * 17);
  float* pduv = alloc(512 * 4); float* pdt = alloc(512 * 2);
  float* pqt  = alloc(512 * 2); float* pzt = alloc(64 * 2);
  float* Wp1f = alloc(9 * 80 * 256 / 2);
  float* Wp2f = alloc(9 * 256 * 96 / 2);
  float* syncf = alloc(8);
  unsigned short* Wp1 = (unsigned short*)Wp1f;
  unsigned short* Wp2 = (unsigned short*)Wp2f;
  unsigned* syncp = (unsigned*)syncf;
  // XT bf16 [8][32][64][256] aliases Ua..k4t; dead before stage1 writes Ua.
  unsigned short* XT = (unsigned short*)Ua;
  // MT bf16 [8][32][64][96] aliases Tb..(into dtA); written in mega P8 after all reads.
  unsigned short* MT = (unsigned short*)Tb;
  // mid aliases Ua..Ta (5*NF == NHB)
  float* mid = Ua;

  // 1. transpose x + pack weights + zero barrier state
  pre_k<<<2608, 256, 0, stream>>>(x, w_norm, w_innorm, XT, Wp1, Wp2, syncp);
  // 2. conv1 (bf16 MFMA implicit GEMM)
  conv_mfma_k<256, 128, 65, 80, 5, 1, 7><<<dim3(32, 8), 5 * 64, 0, stream>>>(XT, Wp1, b_norm, hb);
  // 3. mega: bn1 -> prep -> RK stages -> zt -> outmid -> transpose(mid)
  MegaArgs ma;
  ma.hb = hb; ma.coef = coef; ma.gb = gb;
  ma.Fz = Fz; ma.Fq = Fq; ma.Fu = Fu; ma.Fvf = Fvf; ma.Ft = Ft;
  ma.zx = zx; ma.zy = zy; ma.zz = zz; ma.ux = ux; ma.vy = vy; ma.wv = wvel;
  ma.C0 = C0; ma.prr = prr;
  ma.Ua = Ua; ma.Ub = Ub; ma.Va = Va; ma.Vb = Vb; ma.Ta = Ta; ma.Tb = Tb;
  ma.duA = duA; ma.dvA = dvA; ma.dtA = dtA; ma.k4t = k4t; ma.ztA = ztA; ma.qtA = qtA;
  ma.bnp = bnp; ma.partS = partS; ma.sc1g = sc1g;
  ma.pduv = pduv; ma.pdt = pdt; ma.pqt = pqt; ma.pzt = pzt;
  ma.mid = mid; ma.MT = MT; ma.sync = syncp;
  mega_k<<<512, 256, 0, stream>>>(ma);
  // 4. tail: conv2 + bn2 + residual
  TailArgs ta;
  ta.MT = MT; ta.Wp2 = Wp2; ta.bias = b_innorm;
  ta.yout = yout; ta.x = x; ta.gblk = gblk; ta.bblk = bblk;
  ta.A2 = A2; ta.B2 = B2; ta.sync = syncp + 2;
  tail_k<<<256, 512, 0, stream>>>(ta);
}

// Round 5
// 1230.967 us; speedup vs baseline: 1.2046x; 1.2046x over previous
//
#include <hip/hip_runtime.h>
#include <math.h>

#define DEVFN static __device__ __forceinline__

static constexpr int BB = 8, VV = 13, HH = 32, WW = 64;
static constexpr int NPLANE = HH * WW;        // 2048
static constexpr int NF = BB * VV * NPLANE;   // 212992
static constexpr int NHB = BB * 65 * NPLANE;  // 1064960
static constexpr int GSZ = 512 * 256;         // mega grid threads

static constexpr float DT = 300.0f;
static constexpr float KHc = 15.0f, KVc = 0.1f;
static constexpr float OMEGAc = 7.29e-5f;
static constexpr float L_Vc = 2.5e6f;
static constexpr float R_GASc = 8.314f;
static constexpr float C_Pc = 1005.0f;
static constexpr float PTHc = 0.8f;
static constexpr float PYc  = (float)(3.14159265358979323846 * 6371000.0 / 33.0);
static constexpr float PXCc = (float)(2.0 * 3.14159265358979323846 * 6371000.0 / 64.0);
static constexpr float RCCc = (float)(0.7 * 5.67e-8 * 287.0 / (1005.0 * 100.0));
static constexpr float FBIG = 3.402823466e38f;

__constant__ float cDZ[13]  = {50,50,50,50,50,75,100,100,100,125,112,75,75};
__constant__ float cPRS[13] = {50,100,150,200,250,300,400,500,600,700,850,925,1000};

typedef short bf16x8 __attribute__((ext_vector_type(8)));
typedef float f32x4 __attribute__((ext_vector_type(4)));

DEVFN int pmh(int r){ return r < 0 ? r + 2 : (r > HH - 1 ? r - 2 : r); }
DEVFN int pmv(int r){ return r < 0 ? r + 2 : (r > VV - 1 ? r - 2 : r); }
DEVFN float latOf(int h){ return (90.0f - (float)(h + 1) * (180.0f / 33.0f)) * 0.017453292519943295f; }
DEVFN float avoid_inf(float t){
  if (t == 0.0f) t = 0.1f;
  if (fabsf(t) < 1.0f) t = copysignf(1.0f, t);
  return t;
}
DEVFN unsigned short f2bf(float f){
  unsigned u = __float_as_uint(f);
  unsigned r = (u + 0x7fffu + ((u >> 16) & 1u)) >> 16;
  return (unsigned short)r;
}

// ---- stencils on [B][13][32][64] ----
DEVFN float d_xf(const float* __restrict__ F, int rb, int w, float invpx){
  return (F[rb + ((w + 62) & 63)] - 8.f * F[rb + ((w + 63) & 63)]
        + 8.f * F[rb + ((w + 1) & 63)] - F[rb + ((w + 2) & 63)]) * (1.f / 12.f) * invpx;
}
DEVFN float d_yf(const float* __restrict__ F, int bvbase, int h, int w){
  return (-F[bvbase + pmh(h - 2) * 64 + w] + 8.f * F[bvbase + pmh(h - 1) * 64 + w]
          - 8.f * F[bvbase + pmh(h + 1) * 64 + w] + F[bvbase + pmh(h + 2) * 64 + w]) * (1.f / 12.f) * (1.f / PYc);
}
DEVFN float d_zf(const float* __restrict__ F, int bbase, int v, int hw){
  return (-F[bbase + pmv(v - 2) * 2048 + hw] + 8.f * F[bbase + pmv(v - 1) * 2048 + hw]
          - 8.f * F[bbase + pmv(v + 1) * 2048 + hw] + F[bbase + pmv(v + 2) * 2048 + hw]) * (1.f / 12.f) / cDZ[v];
}
DEVFN float dxxf(const float* __restrict__ F, int rb, int w, float invpx){
  float s = F[rb + ((w + 60) & 63)] - 16.f * F[rb + ((w + 61) & 63)] + 64.f * F[rb + ((w + 62) & 63)]
          + 16.f * F[rb + ((w + 63) & 63)] - 130.f * F[rb + w] + 16.f * F[rb + ((w + 1) & 63)]
          + 64.f * F[rb + ((w + 2) & 63)] - 16.f * F[rb + ((w + 3) & 63)] + F[rb + ((w + 4) & 63)];
  return s * (1.f / 144.f) * invpx * invpx;
}
DEVFN float dyyf(const float* __restrict__ F, int bvbase, int h, int w){
  float g0 = d_yf(F, bvbase, pmh(h - 2), w);
  float g1 = d_yf(F, bvbase, pmh(h - 1), w);
  float g2 = d_yf(F, bvbase, pmh(h + 1), w);
  float g3 = d_yf(F, bvbase, pmh(h + 2), w);
  return (-g0 + 8.f * g1 - 8.f * g2 + g3) * (1.f / 12.f) * (1.f / PYc);
}
DEVFN float dzzf(const float* __restrict__ F, int bbase, int v, int hw){
  float g0 = d_zf(F, bbase, pmv(v - 2), hw);
  float g1 = d_zf(F, bbase, pmv(v - 1), hw);
  float g2 = d_zf(F, bbase, pmv(v + 1), hw);
  float g3 = d_zf(F, bbase, pmv(v + 2), hw);
  return (-g0 + 8.f * g1 - 8.f * g2 + g3) * (1.f / 12.f) / cDZ[v];
}

// ---- reductions ----
DEVFN float waveRedSum(float v){ for (int o = 32; o; o >>= 1) v += __shfl_down(v, o, 64); return v; }
DEVFN float waveRedMin(float v){ for (int o = 32; o; o >>= 1) v = fminf(v, __shfl_down(v, o, 64)); return v; }
DEVFN float waveRedMax(float v){ for (int o = 32; o; o >>= 1) v = fmaxf(v, __shfl_down(v, o, 64)); return v; }

template<int OP, int NWV>
static __device__ float blockRedN(float v){
  __shared__ float s[NWV];
  v = OP == 0 ? waveRedSum(v) : OP == 1 ? waveRedMin(v) : waveRedMax(v);
  int lane = threadIdx.x & 63, wid = threadIdx.x >> 6;
  __syncthreads();
  if (lane == 0) s[wid] = v;
  __syncthreads();
  float r = s[0];
  #pragma unroll
  for (int k = 1; k < NWV; ++k)
    r = OP == 0 ? r + s[k] : OP == 1 ? fminf(r, s[k]) : fmaxf(r, s[k]);
  return r;
}

// ---- contention-free grid barrier: per-block flag store + all-flag poll ----
// Each block STORES its own word (no RMW contention); wave 0 polls all flags.
DEVFN void gridBarF(unsigned* flags, int nblk, unsigned target){
  __syncthreads();
  __threadfence();
  int t = threadIdx.x;
  if (t == 0)
    __hip_atomic_store(&flags[blockIdx.x], target, __ATOMIC_RELEASE, __HIP_MEMORY_SCOPE_AGENT);
  if (t < 64){
    for (int j = t; j < nblk; j += 64){
      while (__hip_atomic_load(&flags[j], __ATOMIC_ACQUIRE, __HIP_MEMORY_SCOPE_AGENT) < target)
        __builtin_amdgcn_s_sleep(1);
    }
  }
  __syncthreads();
  __threadfence();
}

// ================= launch 1: transpose x + pack both weights + zero flags =================
__global__ void __launch_bounds__(256) pre_k(const float* __restrict__ x,
    const float* __restrict__ w1, const float* __restrict__ w2,
    unsigned short* __restrict__ XT, unsigned short* __restrict__ wp1,
    unsigned short* __restrict__ wp2, unsigned* __restrict__ flags)
{
  int blk = blockIdx.x, t = threadIdx.x;
  if (blk < 3) flags[blk * 256 + t] = 0u;
  if (blk < 1024){
    __shared__ float tile[16 * 68];
    int zz = blk >> 8, rem = blk & 255;
    int b = rem >> 5, h = rem & 31;
    for (int p = zz * 4; p < zz * 4 + 4; ++p){
      int cbase = p * 16;
      __syncthreads();
      {
        int cl = t >> 4, w4 = (t & 15) * 4;
        float4 v = *(const float4*)(x + (((size_t)(b * 256 + cbase + cl) * 32 + h) * 64 + w4));
        tile[cl * 68 + w4 + 0] = v.x; tile[cl * 68 + w4 + 1] = v.y;
        tile[cl * 68 + w4 + 2] = v.z; tile[cl * 68 + w4 + 3] = v.w;
      }
      __syncthreads();
      {
        int w = t >> 2, c4 = (t & 3) * 4;
        ushort4 o;
        o.x = f2bf(tile[(c4 + 0) * 68 + w]);
        o.y = f2bf(tile[(c4 + 1) * 68 + w]);
        o.z = f2bf(tile[(c4 + 2) * 68 + w]);
        o.w = f2bf(tile[(c4 + 3) * 68 + w]);
        *(ushort4*)(XT + (((size_t)(b * 32 + h) * 64 + w) * 256 + cbase + c4)) = o;
      }
    }
  } else {
    const int T1 = 9 * 80 * 256;
    const int T2 = 9 * 256 * 96;
    int idx = (blk - 1024) * 256 + t;
    if (idx < T1){
      int dir = idx / (80 * 256);
      int r = idx - dir * (80 * 256);
      int co = r / 256, ci = r - co * 256;
      float v = (co < 65) ? w1[((size_t)(co * 256 + ci)) * 9 + dir] : 0.f;
      wp1[idx] = f2bf(v);
    } else if (idx < T1 + T2){
      int j = idx - T1;
      int dir = j / (256 * 96);
      int r = j - dir * (256 * 96);
      int co = r / 96, ci = r - co * 96;
      float v = (ci < 65) ? w2[((size_t)(co * 65 + ci)) * 9 + dir] : 0.f;
      wp2[j] = f2bf(v);
    }
  }
}

// ================= conv1 via MFMA =================
template<int CIT, int CIL, int CO, int COp, int NW, int MF, int SWZ>
__global__ void __launch_bounds__(NW * 64) conv_mfma_k(
    const unsigned short* __restrict__ XT, const unsigned short* __restrict__ Wp,
    const float* __restrict__ bias, float* __restrict__ out)
{
  __shared__ __align__(16) unsigned short Xl[3 * 66 * CIL];
  const int C8 = CIL / 8;
  int tid = threadIdx.x;
  int h = blockIdx.x, b = blockIdx.y;
  int wid = tid >> 6, lane = tid & 63;
  int l15 = lane & 15, q = lane >> 4;

  f32x4 acc[MF][4];
  #pragma unroll
  for (int mf = 0; mf < MF; ++mf)
    #pragma unroll
    for (int nf = 0; nf < 4; ++nf){ f32x4 z = {0.f, 0.f, 0.f, 0.f}; acc[mf][nf] = z; }

  for (int cp = 0; cp < CIT / CIL; ++cp){
    if (cp) __syncthreads();
    for (int idx = tid; idx < 3 * 64 * C8; idx += NW * 64){
      int r = idx / (64 * C8);
      int rest = idx - r * 64 * C8;
      int j1 = rest / C8;
      int c8 = rest - j1 * C8;
      int j = j1 + 1;
      int hh = h + r - 1;
      uint4 val = make_uint4(0, 0, 0, 0);
      if (hh >= 0 && hh < 32)
        val = *(const uint4*)(XT + (((size_t)(b * 32 + hh) * 64 + j1) * CIT + cp * CIL + c8 * 8));
      int dst = (r * 66 + j) * CIL + ((c8 * 8) ^ ((j & SWZ) << 3));
      *(uint4*)(Xl + dst) = val;
    }
    for (int idx = tid; idx < 3 * 2 * C8; idx += NW * 64){
      int r = idx / (2 * C8);
      int rest = idx - r * 2 * C8;
      int js = rest / C8;
      int c8 = rest - js * C8;
      int j = js ? 65 : 0;
      int dst = (r * 66 + j) * CIL + ((c8 * 8) ^ ((j & SWZ) << 3));
      *(uint4*)(Xl + dst) = make_uint4(0, 0, 0, 0);
    }
    __syncthreads();

    for (int dir = 0; dir < 9; ++dir){
      int dy = dir / 3, dx = dir - dy * 3;
      #pragma unroll
      for (int kc = 0; kc < CIL / 32; ++kc){
        int kb = kc * 32 + q * 8;
        bf16x8 a[MF];
        #pragma unroll
        for (int mf = 0; mf < MF; ++mf){
          int co = wid * (MF * 16) + mf * 16 + l15;
          a[mf] = *(const bf16x8*)(Wp + ((size_t)(dir * COp + co) * CIT + cp * CIL + kb));
        }
        #pragma unroll
        for (int nf = 0; nf < 4; ++nf){
          int j = nf * 16 + l15 + dx;
          bf16x8 bfrag = *(const bf16x8*)(Xl + ((dy * 66 + j) * CIL + (kb ^ ((j & SWZ) << 3))));
          #pragma unroll
          for (int mf = 0; mf < MF; ++mf)
            acc[mf][nf] = __builtin_amdgcn_mfma_f32_16x16x32_bf16(a[mf], bfrag, acc[mf][nf], 0, 0, 0);
        }
      }
    }
  }
  #pragma unroll
  for (int mf = 0; mf < MF; ++mf){
    #pragma unroll
    for (int r = 0; r < 4; ++r){
      int co = wid * (MF * 16) + mf * 16 + q * 4 + r;
      if (CO != COp && co >= CO) continue;
      float bv = bias[co];
      #pragma unroll
      for (int nf = 0; nf < 4; ++nf){
        int pix = nf * 16 + l15;
        out[(size_t)(b * CO + co) * 2048 + h * 64 + pix] = acc[mf][nf][r] + bv;
      }
    }
  }
}

// ================= mega kernel =================
struct GB { const float* g[5]; const float* b[5]; };

struct MegaArgs {
  const float* hb; const float* coef;
  GB gb;
  float *Fz, *Fq, *Fu, *Fvf, *Ft;
  float *zx, *zy, *zz, *ux, *vy, *wv;
  float *C0, *prr;
  float *Ua, *Ub, *Va, *Vb, *Ta, *Tb;
  float *duA, *dvA, *dtA, *k4t, *ztA, *qtA;
  float *bnp, *partS, *sc1g;
  float *pduv, *pdt, *pqt, *pzt;
  unsigned short* MT;
  unsigned* flags;
};

template<int STAGE>
DEVFN void stageBody(int blk, int t,
  const float* __restrict__ U, const float* __restrict__ Vf, const float* __restrict__ T,
  const MegaArgs& a, float ss, float off,
  float* __restrict__ Uo, float* __restrict__ Vo, float* __restrict__ To, float cnext)
{
  int gtid = blk * 256 + t;
  float aumn = FBIG, aumx = -FBIG, avmn = FBIG, avmx = -FBIG, atmn = FBIG, atmx = -FBIG;
  float qmn = FBIG, qmx = -FBIG;
  #pragma unroll 1
  for (int i = gtid; i < NF; i += GSZ){
    int w = i & 63, h = (i >> 6) & 31;
    int bv = i >> 11;
    int v = bv % 13;
    int bvbase = bv * 2048;
    int rb = bvbase + h * 64;
    int bbase = (bv - v) * 2048;
    int hw = h * 64 + w;
    float lat = latOf(h);
    float invpx = 1.0f / (PXCc * cosf(lat));
    float fcor = 2.0f * OMEGAc * sinf(lat);
    float wvi = a.wv[i];
    float Ui = U[i], Vi = Vf[i], Ti = T[i];
    float Fui = (STAGE == 1) ? Ui : a.Fu[i];
    float Fvi = (STAGE == 1) ? Vi : a.Fvf[i];

    float dyU = d_yf(U, bvbase, h, w);
    float dzU = d_zf(U, bbase, v, hw);
    float dxV = d_xf(Vf, rb, w, invpx);
    float dzV = d_zf(Vf, bbase, v, hw);
    float mixU = KHc * (dxxf(U, rb, w, invpx) + dyyf(U, bvbase, h, w)) + KVc * dzzf(U, bbase, v, hw);
    float mixV = KHc * (dxxf(Vf, rb, w, invpx) + dyyf(Vf, bvbase, h, w)) + KVc * dzzf(Vf, bbase, v, hw);
    float ku = -Ui * a.ux[i] - Vi * dyU - wvi * dzU + fcor * Vi - a.zx[i] + mixU;
    float kv = -Ui * dxV - Vi * a.vy[i] - wvi * dzV - fcor * Ui - a.zy[i] + mixV;

    float C0i;
    if (STAGE == 1){
      float zzi = a.zz[i], qi = a.Fq[i];
      float rho = -1.0f / avoid_inf(zzi);
      float p = rho * R_GASc * Ti;
      float tcc = Ti - 273.15f;
      float arg = 17.67f * tcc / avoid_inf(tcc + 243.5f);
      float es = 6.112f * expf(arg * ss + off) * 100.0f;
      float qs = fmaxf(0.622f * es / avoid_inf(p - 0.378f * es), 1e-6f);
      float rh = qi / avoid_inf(qs);
      float rate = (rh > PTHc) ? (qi - PTHc * qs) * (1.0f / DT) : 0.0f;
      a.prr[i] = rate;
      C0i = -(L_Vc + 1.0f) * zzi * wvi * (1.0f / C_Pc) + rate * (L_Vc / C_Pc);
      a.C0[i] = C0i;
    } else {
      C0i = a.C0[i];
    }

    float dxT = d_xf(T, rb, w, invpx);
    float dyT = d_yf(T, bvbase, h, w);
    float dzT = d_zf(T, bbase, v, hw);
    float mixT = KHc * (dxxf(T, rb, w, invpx) + dyyf(T, bvbase, h, w)) + KVc * dzzf(T, bbase, v, hw);
    float ta = Ti + 273.15f;
    float t2 = ta * ta;
    float ta5 = t2 * t2 * ta;
    float rc = -RCCc * ta5 / cPRS[v];
    float kt = C0i - Fui * dxT - Fvi * dyT - wvi * dzT + mixT + rc;

    if (STAGE == 1){ a.duA[i] = ku; a.dvA[i] = kv; a.dtA[i] = kt; }
    else if (STAGE < 4){ a.duA[i] += 2.f * ku; a.dvA[i] += 2.f * kv; a.dtA[i] += 2.f * kt; }
    else {
      float au = a.duA[i] + ku, av = a.dvA[i] + kv, at = a.dtA[i] + kt;
      a.duA[i] = au; a.dvA[i] = av; a.dtA[i] = at; a.k4t[i] = kt;
      aumn = fminf(aumn, au); aumx = fmaxf(aumx, au);
      avmn = fminf(avmn, av); avmx = fmaxf(avmx, av);
      atmn = fminf(atmn, at); atmx = fmaxf(atmx, at);
    }
    if (STAGE < 4){
      float Fti = (STAGE == 1) ? Ti : a.Ft[i];
      Uo[i] = Fui + cnext * ku;
      Vo[i] = Fvi + cnext * kv;
      To[i] = Fti + cnext * kt;
    }
    if (STAGE == 2){
      float qtv = -Fui * d_xf(a.Fq, rb, w, invpx) - Fvi * d_yf(a.Fq, bvbase, h, w) - wvi * d_zf(a.Fq, bbase, v, hw)
                + KHc * (dxxf(a.Fq, rb, w, invpx) + dyyf(a.Fq, bvbase, h, w)) + KVc * dzzf(a.Fq, bbase, v, hw) - a.prr[i];
      a.qtA[i] = qtv;
      qmn = fminf(qmn, qtv); qmx = fmaxf(qmx, qtv);
    }
  }
  if (STAGE == 4){
    float m0 = blockRedN<1,4>(aumn), m1 = blockRedN<2,4>(aumx);
    float m2 = blockRedN<1,4>(avmn), m3 = blockRedN<2,4>(avmx);
    float m4 = blockRedN<1,4>(atmn), m5 = blockRedN<2,4>(atmx);
    if (!t){
      float* pp = a.pduv + blk * 4;
      pp[0] = m0; pp[1] = m1; pp[2] = m2; pp[3] = m3;
      a.pdt[blk * 2] = m4; a.pdt[blk * 2 + 1] = m5;
    }
  }
  if (STAGE == 2){
    float m0 = blockRedN<1,4>(qmn), m1 = blockRedN<2,4>(qmx);
    if (!t){ a.pqt[blk * 2] = m0; a.pqt[blk * 2 + 1] = m1; }
  }
}

__global__ void __launch_bounds__(256, 2) mega_k(MegaArgs a)
{
  __shared__ float As[65], Bs[65];
  __shared__ float tileBig[65 * 66];
  int blk = blockIdx.x, t = threadIdx.x;
  int gtid = blk * 256 + t;
  unsigned* flags = a.flags;

  // ---- P0: BN1 partial sums (per (channel, batch) slice) ----
  #pragma unroll 1
  for (int rep = 0; rep < 2; ++rep){
    int idx = blk + rep * 512;
    if (idx < 520){
      int c = idx % 65, bb = idx / 65;
      const float* src = a.hb + (size_t)(bb * 65 + c) * 2048;
      float s = 0.f, s2 = 0.f;
      for (int j = t; j < 2048; j += 256){ float v = src[j]; s += v; s2 += v * v; }
      s = blockRedN<0,4>(s); s2 = blockRedN<0,4>(s2);
      if (!t){ a.bnp[idx * 2] = s; a.bnp[idx * 2 + 1] = s2; }
    }
  }
  gridBarF(flags, 512, 1);

  // ---- P1: prep (part-per-field, all 512 blocks) ----
  {
    if (t < 65){
      float s = 0.f, s2 = 0.f;
      for (int bb = 0; bb < 8; ++bb){ int idx = t + 65 * bb; s += a.bnp[idx * 2]; s2 += a.bnp[idx * 2 + 1]; }
      float m = s * (1.f / 16384.f);
      float var = s2 * (1.f / 16384.f) - m * m;
      float rstd = rsqrtf(var + 1e-5f);
      int f = t / 13, k = t - f * 13;
      float g = a.gb.g[f][k], bbv = a.gb.b[f][k];
      As[t] = g * rstd; Bs[t] = bbv - m * g * rstd;
    }
    __syncthreads();
    int part = blk >> 6;
    int col = ((blk & 63) << 8) | t;
    int b = col >> 11, p = col & 2047, h = p >> 6, w = p & 63;
    int hbase = b * 65 * NPLANE;
    auto hn = [&](int ch, int hh, int ww)->float {
      return a.hb[hbase + ch * 2048 + hh * 64 + ww] * As[ch] + Bs[ch];
    };
    int fb = (b * 13) * 2048 + p;
    float lat = latOf(h);
    float invpx = 1.0f / (PXCc * cosf(lat));
    int wm2 = (w + 62) & 63, wm1 = (w + 63) & 63, wp1 = (w + 1) & 63, wp2v = (w + 2) & 63;
    int hm2 = pmh(h - 2), hm1 = pmh(h - 1), hp1 = pmh(h + 1), hp2 = pmh(h + 2);
    float fmn = FBIG, fmx = -FBIG, fsm = 0.f, smn = FBIG, smx = -FBIG;
    if (part < 5){
      int ch0 = part * 13;
      float c[13];
      #pragma unroll
      for (int v = 0; v < 13; ++v) c[v] = hn(ch0 + v, h, w);
      float* Fdst = part == 0 ? a.Fz : part == 1 ? a.Fq : part == 2 ? a.Fu : part == 3 ? a.Fvf : a.Ft;
      #pragma unroll
      for (int v = 0; v < 13; ++v) Fdst[fb + v * 2048] = c[v];
      if (part == 0){
        #pragma unroll
        for (int v = 0; v < 13; ++v){
          a.zz[fb + v * 2048] = (-c[pmv(v - 2)] + 8.f * c[pmv(v - 1)] - 8.f * c[pmv(v + 1)] + c[pmv(v + 2)]) * (1.f / 12.f) / cDZ[v];
          float zxv = (hn(v, h, wm2) - 8.f * hn(v, h, wm1) + 8.f * hn(v, h, wp1) - hn(v, h, wp2v)) * (1.f / 12.f) * invpx;
          float zyv = (-hn(v, hm2, w) + 8.f * hn(v, hm1, w) - 8.f * hn(v, hp1, w) + hn(v, hp2, w)) * (1.f / 12.f) * (1.f / PYc);
          a.zx[fb + v * 2048] = zxv; a.zy[fb + v * 2048] = zyv;
        }
      }
      if (part == 2){
        #pragma unroll
        for (int v = 0; v < 13; ++v){
          float uxv = (hn(26 + v, h, wm2) - 8.f * hn(26 + v, h, wm1) + 8.f * hn(26 + v, h, wp1) - hn(26 + v, h, wp2v)) * (1.f / 12.f) * invpx;
          a.ux[fb + v * 2048] = uxv;
        }
      }
      if (part == 3){
        #pragma unroll
        for (int v = 0; v < 13; ++v){
          float vyv = (-hn(39 + v, hm2, w) + 8.f * hn(39 + v, hm1, w) - 8.f * hn(39 + v, hp1, w) + hn(39 + v, hp2, w)) * (1.f / 12.f) * (1.f / PYc);
          a.vy[fb + v * 2048] = vyv;
        }
      }
      if (part == 4){
        #pragma unroll
        for (int v = 0; v < 13; ++v){
          float tcc = c[v] - 273.15f;
          float arg = 17.67f * tcc / avoid_inf(tcc + 243.5f);
          smn = fminf(smn, arg); smx = fmaxf(smx, arg);
        }
      }
      #pragma unroll
      for (int v = 0; v < 13; ++v){ fmn = fminf(fmn, c[v]); fmx = fmaxf(fmx, c[v]); fsm += c[v]; }
    } else if (part == 5){
      float cum = 0.f;
      #pragma unroll
      for (int v = 0; v < 13; ++v){
        float uxv = (hn(26 + v, h, wm2) - 8.f * hn(26 + v, h, wm1) + 8.f * hn(26 + v, h, wp1) - hn(26 + v, h, wp2v)) * (1.f / 12.f) * invpx;
        float vyv = (-hn(39 + v, hm2, w) + 8.f * hn(39 + v, hm1, w) - 8.f * hn(39 + v, hp1, w) + hn(39 + v, hp2, w)) * (1.f / 12.f) * (1.f / PYc);
        cum += cDZ[v] * (uxv + vyv);
        a.wv[fb + v * 2048] = -cum;
      }
    }
    float* pb = a.partS + blk * 17;
    float r;
    r = blockRedN<1,4>(smn); if (!t) pb[0] = r;
    r = blockRedN<2,4>(smx); if (!t) pb[1] = r;
    #pragma unroll
    for (int f = 0; f < 5; ++f){
      r = blockRedN<1,4>(part == f ? fmn : FBIG);  if (!t) pb[2 + f * 3] = r;
      r = blockRedN<2,4>(part == f ? fmx : -FBIG); if (!t) pb[3 + f * 3] = r;
      r = blockRedN<0,4>(part == f ? fsm : 0.f);   if (!t) pb[4 + f * 3] = r;
    }
  }
  gridBarF(flags, 512, 2);

  // ---- P2: redundant sc1 reduce + RK stage 1 ----
  float ss, off;
  {
    float smn = FBIG, smx = -FBIG;
    float fmn[5] = {FBIG, FBIG, FBIG, FBIG, FBIG};
    float fmx[5] = {-FBIG, -FBIG, -FBIG, -FBIG, -FBIG};
    float fsm[5] = {0.f, 0.f, 0.f, 0.f, 0.f};
    #pragma unroll 1
    for (int r0 = t; r0 < 512; r0 += 256){
      const float* pr = a.partS + r0 * 17;
      smn = fminf(smn, pr[0]); smx = fmaxf(smx, pr[1]);
      #pragma unroll
      for (int f = 0; f < 5; ++f){
        fmn[f] = fminf(fmn[f], pr[2 + f * 3]);
        fmx[f] = fmaxf(fmx[f], pr[3 + f * 3]);
        fsm[f] += pr[4 + f * 3];
      }
    }
    smn = blockRedN<1,4>(smn); smx = blockRedN<2,4>(smx);
    #pragma unroll
    for (int f = 0; f < 5; ++f){
      fmn[f] = blockRedN<1,4>(fmn[f]);
      fmx[f] = blockRedN<2,4>(fmx[f]);
      fsm[f] = blockRedN<0,4>(fsm[f]);
    }
    ss = (3.01f + 3.47f) / (smx - smn);
    off = -3.47f - smn * ss;
    if (blk == 0 && t == 0){
      a.sc1g[0] = ss; a.sc1g[1] = off;
      #pragma unroll
      for (int f = 0; f < 5; ++f){
        a.sc1g[2 + f * 3] = fmn[f];
        a.sc1g[3 + f * 3] = fsm[f] * (1.0f / (float)NF);
        a.sc1g[4 + f * 3] = fmx[f];
      }
    }
  }
  stageBody<1>(blk, t, a.Fu, a.Fvf, a.Ft, a, ss, off, a.Ua, a.Va, a.Ta, 0.5f * DT);
  gridBarF(flags, 512, 3);
  stageBody<2>(blk, t, a.Ua, a.Va, a.Ta, a, ss, off, a.Ub, a.Vb, a.Tb, 0.5f * DT);
  gridBarF(flags, 512, 4);
  stageBody<3>(blk, t, a.Ub, a.Vb, a.Tb, a, ss, off, a.Ua, a.Va, a.Ta, DT);
  gridBarF(flags, 512, 5);
  stageBody<4>(blk, t, a.Ua, a.Va, a.Ta, a, ss, off, (float*)0, (float*)0, (float*)0, 0.f);
  gridBarF(flags, 512, 6);

  // ---- P6: z-tendency integral ----
  if (blk < 64){
    int col = blk * 256 + t;
    int b = col >> 11, p = col & 2047;
    int fb = b * 13 * 2048 + p;
    float cum = 0.f, mn = FBIG, mx = -FBIG;
    #pragma unroll
    for (int v = 0; v < 13; ++v){
      cum += cDZ[v] * (-R_GASc / cPRS[v]) * a.k4t[fb + v * 2048];
      a.ztA[fb + v * 2048] = cum;
      mn = fminf(mn, cum); mx = fmaxf(mx, cum);
    }
    mn = blockRedN<1,4>(mn); mx = blockRedN<2,4>(mx);
    if (!t){ a.pzt[blk * 2] = mn; a.pzt[blk * 2 + 1] = mx; }
  }
  gridBarF(flags, 512, 7);

  // ---- P7+P8 fused: redundant sc2 reduce + outmid into LDS + bf16 transpose out ----
  {
    float dumn = FBIG, dumx = -FBIG, dvmn = FBIG, dvmx = -FBIG, dtmn2 = FBIG, dtmx2 = -FBIG;
    float qmn = FBIG, qmx = -FBIG;
    #pragma unroll 1
    for (int r0 = t; r0 < 512; r0 += 256){
      dumn = fminf(dumn, a.pduv[r0 * 4]);     dumx = fmaxf(dumx, a.pduv[r0 * 4 + 1]);
      dvmn = fminf(dvmn, a.pduv[r0 * 4 + 2]); dvmx = fmaxf(dvmx, a.pduv[r0 * 4 + 3]);
      dtmn2 = fminf(dtmn2, a.pdt[r0 * 2]);    dtmx2 = fmaxf(dtmx2, a.pdt[r0 * 2 + 1]);
      qmn = fminf(qmn, a.pqt[r0 * 2]);        qmx = fmaxf(qmx, a.pqt[r0 * 2 + 1]);
    }
    float zmn = (t < 64) ? a.pzt[t * 2] : FBIG;
    float zmx = (t < 64) ? a.pzt[t * 2 + 1] : -FBIG;
    dumn = blockRedN<1,4>(dumn); dumx = blockRedN<2,4>(dumx);
    dvmn = blockRedN<1,4>(dvmn); dvmx = blockRedN<2,4>(dvmx);
    dtmn2 = blockRedN<1,4>(dtmn2); dtmx2 = blockRedN<2,4>(dtmx2);
    qmn = blockRedN<1,4>(qmn);   qmx = blockRedN<2,4>(qmx);
    zmn = blockRedN<1,4>(zmn);   zmx = blockRedN<2,4>(zmx);

    float scf[5], off2[5];
    {
      float rmn[5] = {zmn, qmn, dumn, dvmn, dtmn2};
      float rmx[5] = {zmx, qmx, dumx, dvmx, dtmx2};
      float cfs[5] = {DT, DT, DT / 6.f, DT / 6.f, DT / 6.f};
      #pragma unroll
      for (int f = 0; f < 5; ++f){
        float mnf = a.sc1g[2 + f * 3], mef = a.sc1g[3 + f * 3], mxf = a.sc1g[4 + f * 3];
        float aa = (mnf - mef) * 0.05f, b2 = (mxf - mef) * 0.05f;
        float cf = cfs[f];
        float dmn = rmn[f] * cf, dmx = rmx[f] * cf;
        float s = (b2 - aa) / (dmx - dmn);
        scf[f] = s * cf; off2[f] = aa - dmn * s;
      }
    }

    if (blk < 256){
      int b = blk >> 5, h = blk & 31;
      // compute mid for this (b,h) slice into LDS tile [c][w]
      #pragma unroll 1
      for (int idx = t; idx < 65 * 64; idx += 256){
        int c = idx >> 6, w = idx & 63;
        int f = c / 13, v = c - f * 13;
        int fi = (b * 13 + v) * 2048 + h * 64 + w;
        const float *Fp, *Rp;
        switch (f){
          case 0: Fp = a.Fz;  Rp = a.ztA; break;
          case 1: Fp = a.Fq;  Rp = a.qtA; break;
          case 2: Fp = a.Fu;  Rp = a.duA; break;
          case 3: Fp = a.Fvf; Rp = a.dvA; break;
          default: Fp = a.Ft; Rp = a.dtA; break;
        }
        float phys = Fp[fi] + Rp[fi] * scf[f] + off2[f];
        float cf = a.coef[c * 2048 + h * 64 + w];
        float hbv = a.hb[((size_t)(b * 65 + c)) * 2048 + h * 64 + w];
        tileBig[c * 66 + w] = cf * phys + (1.0f - cf) * hbv;
      }
      __syncthreads();
      // transpose to MT bf16 [b][h][w][96]
      #pragma unroll 1
      for (int ph = 0; ph < 6; ++ph){
        int cbase = ph * 16;
        int w = t >> 2, c4 = (t & 3) * 4;
        ushort4 o;
        int c0 = cbase + c4;
        o.x = (c0 + 0 < 65) ? f2bf(tileBig[(c0 + 0) * 66 + w]) : (unsigned short)0;
        o.y = (c0 + 1 < 65) ? f2bf(tileBig[(c0 + 1) * 66 + w]) : (unsigned short)0;
        o.z = (c0 + 2 < 65) ? f2bf(tileBig[(c0 + 2) * 66 + w]) : (unsigned short)0;
        o.w = (c0 + 3 < 65) ? f2bf(tileBig[(c0 + 3) * 66 + w]) : (unsigned short)0;
        *(ushort4*)(a.MT + (((size_t)(b * 32 + h) * 64 + w) * 96 + c0)) = o;
      }
    }
  }
}

// ================= tail: conv2 + BN2 + residual =================
struct TailArgs {
  const unsigned short* MT; const unsigned short* Wp2; const float* bias;
  float* yout; const float* x; const float* gblk; const float* bblk;
  float* A2; float* B2; unsigned* flags;
};

__global__ void __launch_bounds__(512, 2) tail_k(TailArgs a)
{
  constexpr int CIL = 96, SWZ = 3, NW = 8, MF = 2;
  __shared__ __align__(16) unsigned short Xl[3 * 66 * CIL];
  const int C8 = CIL / 8;
  int tid = threadIdx.x;
  int blk = blockIdx.x;

  // ---- conv2 ----
  {
    int h = blk & 31, b = blk >> 5;
    int wid = tid >> 6, lane = tid & 63;
    int l15 = lane & 15, q = lane >> 4;
    f32x4 acc[MF][4];
    #pragma unroll
    for (int mf = 0; mf < MF; ++mf)
      #pragma unroll
      for (int nf = 0; nf < 4; ++nf){ f32x4 z = {0.f, 0.f, 0.f, 0.f}; acc[mf][nf] = z; }

    for (int idx = tid; idx < 3 * 64 * C8; idx += NW * 64){
      int r = idx / (64 * C8);
      int rest = idx - r * 64 * C8;
      int j1 = rest / C8;
      int c8 = rest - j1 * C8;
      int j = j1 + 1;
      int hh = h + r - 1;
      uint4 val = make_uint4(0, 0, 0, 0);
      if (hh >= 0 && hh < 32)
        val = *(const uint4*)(a.MT + (((size_t)(b * 32 + hh) * 64 + j1) * 96 + c8 * 8));
      int dst = (r * 66 + j) * CIL + ((c8 * 8) ^ ((j & SWZ) << 3));
      *(uint4*)(Xl + dst) = val;
    }
    for (int idx = tid; idx < 3 * 2 * C8; idx += NW * 64){
      int r = idx / (2 * C8);
      int rest = idx - r * 2 * C8;
      int js = rest / C8;
      int c8 = rest - js * C8;
      int j = js ? 65 : 0;
      int dst = (r * 66 + j) * CIL + ((c8 * 8) ^ ((j & SWZ) << 3));
      *(uint4*)(Xl + dst) = make_uint4(0, 0, 0, 0);
    }
    __syncthreads();

    for (int dir = 0; dir < 9; ++dir){
      int dy = dir / 3, dx = dir - dy * 3;
      #pragma unroll
      for (int kc = 0; kc < CIL / 32; ++kc){
        int kb = kc * 32 + q * 8;
        bf16x8 afr[MF];
        #pragma unroll
        for (int mf = 0; mf < MF; ++mf){
          int co = wid * (MF * 16) + mf * 16 + l15;
          afr[mf] = *(const bf16x8*)(a.Wp2 + ((size_t)(dir * 256 + co) * 96 + kb));
        }
        #pragma unroll
        for (int nf = 0; nf < 4; ++nf){
          int j = nf * 16 + l15 + dx;
          bf16x8 bfrag = *(const bf16x8*)(Xl + ((dy * 66 + j) * CIL + (kb ^ ((j & SWZ) << 3))));
          #pragma unroll
          for (int mf = 0; mf < MF; ++mf)
            acc[mf][nf] = __builtin_amdgcn_mfma_f32_16x16x32_bf16(afr[mf], bfrag, acc[mf][nf], 0, 0, 0);
        }
      }
    }
    #pragma unroll
    for (int mf = 0; mf < MF; ++mf){
      #pragma unroll
      for (int r = 0; r < 4; ++r){
        int co = wid * (MF * 16) + mf * 16 + q * 4 + r;
        float bv = a.bias[co];
        #pragma unroll
        for (int nf = 0; nf < 4; ++nf){
          int pix = nf * 16 + l15;
          a.yout[(size_t)(b * 256 + co) * 2048 + h * 64 + pix] = acc[mf][nf][r] + bv;
        }
      }
    }
  }
  gridBarF(a.flags, 256, 1);

  // ---- BN2 stats (block = channel) ----
  {
    int c = blk;
    float s = 0.f, s2 = 0.f;
    for (int j = tid; j < 16384; j += 512){
      int b = j >> 11, p = j & 2047;
      float v = a.yout[(size_t)(b * 256 + c) * 2048 + p];
      s += v; s2 += v * v;
    }
    s = blockRedN<0,8>(s); s2 = blockRedN<0,8>(s2);
    if (!tid){
      float m = s * (1.0f / 16384.0f);
      float var = s2 * (1.0f / 16384.0f) - m * m;
      float rstd = rsqrtf(var + 1e-5f);
      a.A2[c] = a.gblk[c] * rstd; a.B2[c] = a.bblk[c] - m * a.gblk[c] * rstd;
    }
  }
  gridBarF(a.flags, 256, 2);

  // ---- apply BN + residual ----
  {
    int gtid = blk * 512 + tid;
    #pragma unroll 1
    for (int e4 = gtid; e4 < 1048576; e4 += 131072){
      int c = (e4 >> 9) & 255;
      float4 v = ((const float4*)a.yout)[e4];
      float4 xv = ((const float4*)a.x)[e4];
      float aa = a.A2[c], bb = a.B2[c];
      v.x = v.x * aa + bb + xv.x;
      v.y = v.y * aa + bb + xv.y;
      v.z = v.z * aa + bb + xv.z;
      v.w = v.w * aa + bb + xv.w;
      ((float4*)a.yout)[e4] = v;
    }
  }
}

extern "C" void kernel_launch(void* const* d_in, const int* in_sizes, int n_in,
                              void* d_out, int out_size, void* d_ws, size_t ws_size,
                              hipStream_t stream)
{
  (void)in_sizes; (void)n_in; (void)out_size; (void)ws_size;
  const float* x        = (const float*)d_in[0];
  const float* w_norm   = (const float*)d_in[1];
  const float* b_norm   = (const float*)d_in[2];
  const float* w_innorm = (const float*)d_in[3];
  const float* b_innorm = (const float*)d_in[4];
  const float* coef     = (const float*)d_in[5];
  GB gb;
  for (int f = 0; f < 5; ++f){
    gb.g[f] = (const float*)d_in[6 + 2 * f];
    gb.b[f] = (const float*)d_in[7 + 2 * f];
  }
  const float* gblk = (const float*)d_in[16];
  const float* bblk = (const float*)d_in[17];
  float* yout = (float*)d_out;

  float* ws = (float*)d_ws;
  size_t off = 0;
  auto alloc = [&](size_t n){ float* p = ws + off; off += n; return p; };
  float* hb  = alloc(NHB);
  float* Fz  = alloc(NF); float* Fq  = alloc(NF); float* Fu  = alloc(NF);
  float* Fvf = alloc(NF); float* Ft  = alloc(NF);
  float* zx  = alloc(NF); float* zy  = alloc(NF); float* zz  = alloc(NF);
  float* ux  = alloc(NF); float* vy  = alloc(NF); float* wvel = alloc(NF);
  float* C0  = alloc(NF); float* prr = alloc(NF);
  float* Ua  = alloc(NF); float* Ub  = alloc(NF); float* Va  = alloc(NF); float* Vb = alloc(NF);
  float* Ta  = alloc(NF); float* Tb  = alloc(NF);
  float* duA = alloc(NF); float* dvA = alloc(NF); float* dtA = alloc(NF);
  float* k4t = alloc(NF); float* ztA = alloc(NF); float* qtA = alloc(NF);
  float* A2 = alloc(256); float* B2 = alloc(256);
  float* sc1g = alloc(32);
  float* bnp = alloc(1040);
  float* partS = alloc(512 * 17);
  float* pduv = alloc(512 * 4); float* pdt = alloc(512 * 2);
  float* pqt  = alloc(512 * 2); float* pzt = alloc(64 * 2);
  float* Wp1f = alloc(9 * 80 * 256 / 2);
  float* Wp2f = alloc(9 * 256 * 96 / 2);
  float* flagsF = alloc(768);
  unsigned short* Wp1 = (unsigned short*)Wp1f;
  unsigned short* Wp2 = (unsigned short*)Wp2f;
  unsigned* flags1 = (unsigned*)flagsF;        // 512 for mega
  unsigned* flags2 = ((unsigned*)flagsF) + 512; // 256 for tail
  // XT bf16 [8][32][64][256] aliases Ua..k4t; dead before stage1 writes Ua.
  unsigned short* XT = (unsigned short*)Ua;
  // MT bf16 [8][32][64][96] (3.14MB) aliases Ua..Vb+ (stage buffers dead after stage4;
  // duA/dvA/dtA/k4t/ztA/qtA NOT overlapped — they are read while MT is written).
  unsigned short* MT = (unsigned short*)Ua;

  // 1. transpose x + pack weights + zero barrier flags
  pre_k<<<2608, 256, 0, stream>>>(x, w_norm, w_innorm, XT, Wp1, Wp2, flags1);
  // 2. conv1 (bf16 MFMA implicit GEMM)
  conv_mfma_k<256, 128, 65, 80, 5, 1, 7><<<dim3(32, 8), 5 * 64, 0, stream>>>(XT, Wp1, b_norm, hb);
  // 3. mega: bn1 -> prep -> RK stages -> zt -> outmid+transpose
  MegaArgs ma;
  ma.hb = hb; ma.coef = coef; ma.gb = gb;
  ma.Fz = Fz; ma.Fq = Fq; ma.Fu = Fu; ma.Fvf = Fvf; ma.Ft = Ft;
  ma.zx = zx; ma.zy = zy; ma.zz = zz; ma.ux = ux; ma.vy = vy; ma.wv = wvel;
  ma.C0 = C0; ma.prr = prr;
  ma.Ua = Ua; ma.Ub = Ub; ma.Va = Va; ma.Vb = Vb; ma.Ta = Ta; ma.Tb = Tb;
  ma.duA = duA; ma.dvA = dvA; ma.dtA = dtA; ma.k4t = k4t; ma.ztA = ztA; ma.qtA = qtA;
  ma.bnp = bnp; ma.partS = partS; ma.sc1g = sc1g;
  ma.pduv = pduv; ma.pdt = pdt; ma.pqt = pqt; ma.pzt = pzt;
  ma.MT = MT; ma.flags = flags1;
  mega_k<<<512, 256, 0, stream>>>(ma);
  // 4. tail: conv2 + bn2 + residual
  TailArgs ta;
  ta.MT = MT; ta.Wp2 = Wp2; ta.bias = b_innorm;
  ta.yout = yout; ta.x = x; ta.gblk = gblk; ta.bblk = bblk;
  ta.A2 = A2; ta.B2 = B2; ta.flags = flags2;
  tail_k<<<256, 512, 0, stream>>>(ta);
}

// Round 6
// 213.393 us; speedup vs baseline: 6.9490x; 5.7686x over previous
//
#include <hip/hip_runtime.h>
#include <math.h>

#define DEVFN static __device__ __forceinline__

static constexpr int BB = 8, VV = 13, HH = 32, WW = 64;
static constexpr int NPLANE = HH * WW;        // 2048
static constexpr int NF = BB * VV * NPLANE;   // 212992
static constexpr int NHB = BB * 65 * NPLANE;  // 1064960
static constexpr int NCOL = BB * NPLANE;      // 16384

static constexpr float DT = 300.0f;
static constexpr float KHc = 15.0f, KVc = 0.1f;
static constexpr float OMEGAc = 7.29e-5f;
static constexpr float L_Vc = 2.5e6f;
static constexpr float R_GASc = 8.314f;
static constexpr float C_Pc = 1005.0f;
static constexpr float PTHc = 0.8f;
static constexpr float PYc  = (float)(3.14159265358979323846 * 6371000.0 / 33.0);
static constexpr float PXCc = (float)(2.0 * 3.14159265358979323846 * 6371000.0 / 64.0);
static constexpr float RCCc = (float)(0.7 * 5.67e-8 * 287.0 / (1005.0 * 100.0));
static constexpr float FBIG = 3.402823466e38f;

__constant__ float cDZ[13]  = {50,50,50,50,50,75,100,100,100,125,112,75,75};
__constant__ float cPRS[13] = {50,100,150,200,250,300,400,500,600,700,850,925,1000};

typedef short bf16x8 __attribute__((ext_vector_type(8)));
typedef float f32x4 __attribute__((ext_vector_type(4)));

DEVFN int pmh(int r){ return r < 0 ? r + 2 : (r > HH - 1 ? r - 2 : r); }
DEVFN int pmv(int r){ return r < 0 ? r + 2 : (r > VV - 1 ? r - 2 : r); }
DEVFN float latOf(int h){ return (90.0f - (float)(h + 1) * (180.0f / 33.0f)) * 0.017453292519943295f; }
DEVFN float avoid_inf(float t){
  if (t == 0.0f) t = 0.1f;
  if (fabsf(t) < 1.0f) t = copysignf(1.0f, t);
  return t;
}
DEVFN unsigned short f2bf(float f){
  unsigned u = __float_as_uint(f);
  unsigned r = (u + 0x7fffu + ((u >> 16) & 1u)) >> 16;
  return (unsigned short)r;
}

// ---- stencils on [B][13][32][64] ----
DEVFN float d_xf(const float* __restrict__ F, int rb, int w, float invpx){
  return (F[rb + ((w + 62) & 63)] - 8.f * F[rb + ((w + 63) & 63)]
        + 8.f * F[rb + ((w + 1) & 63)] - F[rb + ((w + 2) & 63)]) * (1.f / 12.f) * invpx;
}
DEVFN float d_yf(const float* __restrict__ F, int bvbase, int h, int w){
  return (-F[bvbase + pmh(h - 2) * 64 + w] + 8.f * F[bvbase + pmh(h - 1) * 64 + w]
          - 8.f * F[bvbase + pmh(h + 1) * 64 + w] + F[bvbase + pmh(h + 2) * 64 + w]) * (1.f / 12.f) * (1.f / PYc);
}
DEVFN float d_zf(const float* __restrict__ F, int bbase, int v, int hw){
  return (-F[bbase + pmv(v - 2) * 2048 + hw] + 8.f * F[bbase + pmv(v - 1) * 2048 + hw]
          - 8.f * F[bbase + pmv(v + 1) * 2048 + hw] + F[bbase + pmv(v + 2) * 2048 + hw]) * (1.f / 12.f) / cDZ[v];
}
DEVFN float dxxf(const float* __restrict__ F, int rb, int w, float invpx){
  float s = F[rb + ((w + 60) & 63)] - 16.f * F[rb + ((w + 61) & 63)] + 64.f * F[rb + ((w + 62) & 63)]
          + 16.f * F[rb + ((w + 63) & 63)] - 130.f * F[rb + w] + 16.f * F[rb + ((w + 1) & 63)]
          + 64.f * F[rb + ((w + 2) & 63)] - 16.f * F[rb + ((w + 3) & 63)] + F[rb + ((w + 4) & 63)];
  return s * (1.f / 144.f) * invpx * invpx;
}
DEVFN float dyyf(const float* __restrict__ F, int bvbase, int h, int w){
  float g0 = d_yf(F, bvbase, pmh(h - 2), w);
  float g1 = d_yf(F, bvbase, pmh(h - 1), w);
  float g2 = d_yf(F, bvbase, pmh(h + 1), w);
  float g3 = d_yf(F, bvbase, pmh(h + 2), w);
  return (-g0 + 8.f * g1 - 8.f * g2 + g3) * (1.f / 12.f) * (1.f / PYc);
}
DEVFN float dzzf(const float* __restrict__ F, int bbase, int v, int hw){
  float g0 = d_zf(F, bbase, pmv(v - 2), hw);
  float g1 = d_zf(F, bbase, pmv(v - 1), hw);
  float g2 = d_zf(F, bbase, pmv(v + 1), hw);
  float g3 = d_zf(F, bbase, pmv(v + 2), hw);
  return (-g0 + 8.f * g1 - 8.f * g2 + g3) * (1.f / 12.f) / cDZ[v];
}

// ---- reductions ----
DEVFN float waveRedSum(float v){ for (int o = 32; o; o >>= 1) v += __shfl_down(v, o, 64); return v; }
DEVFN float waveRedMin(float v){ for (int o = 32; o; o >>= 1) v = fminf(v, __shfl_down(v, o, 64)); return v; }
DEVFN float waveRedMax(float v){ for (int o = 32; o; o >>= 1) v = fmaxf(v, __shfl_down(v, o, 64)); return v; }

template<int OP, int NWV>
static __device__ float blockRedN(float v){
  __shared__ float s[NWV];
  v = OP == 0 ? waveRedSum(v) : OP == 1 ? waveRedMin(v) : waveRedMax(v);
  int lane = threadIdx.x & 63, wid = threadIdx.x >> 6;
  __syncthreads();
  if (lane == 0) s[wid] = v;
  __syncthreads();
  float r = s[0];
  #pragma unroll
  for (int k = 1; k < NWV; ++k)
    r = OP == 0 ? r + s[k] : OP == 1 ? fminf(r, s[k]) : fmaxf(r, s[k]);
  return r;
}

// ================= launch 1: transpose x + pack both weights =================
__global__ void __launch_bounds__(256) pre_k(const float* __restrict__ x,
    const float* __restrict__ w1, const float* __restrict__ w2,
    unsigned short* __restrict__ XT, unsigned short* __restrict__ wp1,
    unsigned short* __restrict__ wp2)
{
  int blk = blockIdx.x, t = threadIdx.x;
  if (blk < 1024){
    __shared__ float tile[16 * 68];
    int zz = blk >> 8, rem = blk & 255;
    int b = rem >> 5, h = rem & 31;
    for (int p = zz * 4; p < zz * 4 + 4; ++p){
      int cbase = p * 16;
      __syncthreads();
      {
        int cl = t >> 4, w4 = (t & 15) * 4;
        float4 v = *(const float4*)(x + (((size_t)(b * 256 + cbase + cl) * 32 + h) * 64 + w4));
        tile[cl * 68 + w4 + 0] = v.x; tile[cl * 68 + w4 + 1] = v.y;
        tile[cl * 68 + w4 + 2] = v.z; tile[cl * 68 + w4 + 3] = v.w;
      }
      __syncthreads();
      {
        int w = t >> 2, c4 = (t & 3) * 4;
        ushort4 o;
        o.x = f2bf(tile[(c4 + 0) * 68 + w]);
        o.y = f2bf(tile[(c4 + 1) * 68 + w]);
        o.z = f2bf(tile[(c4 + 2) * 68 + w]);
        o.w = f2bf(tile[(c4 + 3) * 68 + w]);
        *(ushort4*)(XT + (((size_t)(b * 32 + h) * 64 + w) * 256 + cbase + c4)) = o;
      }
    }
  } else {
    const int T1 = 9 * 80 * 256;
    const int T2 = 9 * 256 * 96;
    int idx = (blk - 1024) * 256 + t;
    if (idx < T1){
      int dir = idx / (80 * 256);
      int r = idx - dir * (80 * 256);
      int co = r / 256, ci = r - co * 256;
      float v = (co < 65) ? w1[((size_t)(co * 256 + ci)) * 9 + dir] : 0.f;
      wp1[idx] = f2bf(v);
    } else if (idx < T1 + T2){
      int j = idx - T1;
      int dir = j / (256 * 96);
      int r = j - dir * (256 * 96);
      int co = r / 96, ci = r - co * 96;
      float v = (ci < 65) ? w2[((size_t)(co * 65 + ci)) * 9 + dir] : 0.f;
      wp2[j] = f2bf(v);
    }
  }
}

// ================= conv via MFMA =================
template<int CIT, int CIL, int CO, int COp, int NW, int MF, int SWZ>
__global__ void __launch_bounds__(NW * 64) conv_mfma_k(
    const unsigned short* __restrict__ XT, const unsigned short* __restrict__ Wp,
    const float* __restrict__ bias, float* __restrict__ out)
{
  __shared__ __align__(16) unsigned short Xl[3 * 66 * CIL];
  const int C8 = CIL / 8;
  int tid = threadIdx.x;
  int h = blockIdx.x, b = blockIdx.y;
  int wid = tid >> 6, lane = tid & 63;
  int l15 = lane & 15, q = lane >> 4;

  f32x4 acc[MF][4];
  #pragma unroll
  for (int mf = 0; mf < MF; ++mf)
    #pragma unroll
    for (int nf = 0; nf < 4; ++nf){ f32x4 z = {0.f, 0.f, 0.f, 0.f}; acc[mf][nf] = z; }

  for (int cp = 0; cp < CIT / CIL; ++cp){
    if (cp) __syncthreads();
    for (int idx = tid; idx < 3 * 64 * C8; idx += NW * 64){
      int r = idx / (64 * C8);
      int rest = idx - r * 64 * C8;
      int j1 = rest / C8;
      int c8 = rest - j1 * C8;
      int j = j1 + 1;
      int hh = h + r - 1;
      uint4 val = make_uint4(0, 0, 0, 0);
      if (hh >= 0 && hh < 32)
        val = *(const uint4*)(XT + (((size_t)(b * 32 + hh) * 64 + j1) * CIT + cp * CIL + c8 * 8));
      int dst = (r * 66 + j) * CIL + ((c8 * 8) ^ ((j & SWZ) << 3));
      *(uint4*)(Xl + dst) = val;
    }
    for (int idx = tid; idx < 3 * 2 * C8; idx += NW * 64){
      int r = idx / (2 * C8);
      int rest = idx - r * 2 * C8;
      int js = rest / C8;
      int c8 = rest - js * C8;
      int j = js ? 65 : 0;
      int dst = (r * 66 + j) * CIL + ((c8 * 8) ^ ((j & SWZ) << 3));
      *(uint4*)(Xl + dst) = make_uint4(0, 0, 0, 0);
    }
    __syncthreads();

    for (int dir = 0; dir < 9; ++dir){
      int dy = dir / 3, dx = dir - dy * 3;
      #pragma unroll
      for (int kc = 0; kc < CIL / 32; ++kc){
        int kb = kc * 32 + q * 8;
        bf16x8 a[MF];
        #pragma unroll
        for (int mf = 0; mf < MF; ++mf){
          int co = wid * (MF * 16) + mf * 16 + l15;
          a[mf] = *(const bf16x8*)(Wp + ((size_t)(dir * COp + co) * CIT + cp * CIL + kb));
        }
        #pragma unroll
        for (int nf = 0; nf < 4; ++nf){
          int j = nf * 16 + l15 + dx;
          bf16x8 bfrag = *(const bf16x8*)(Xl + ((dy * 66 + j) * CIL + (kb ^ ((j & SWZ) << 3))));
          #pragma unroll
          for (int mf = 0; mf < MF; ++mf)
            acc[mf][nf] = __builtin_amdgcn_mfma_f32_16x16x32_bf16(a[mf], bfrag, acc[mf][nf], 0, 0, 0);
        }
      }
    }
  }
  #pragma unroll
  for (int mf = 0; mf < MF; ++mf){
    #pragma unroll
    for (int r = 0; r < 4; ++r){
      int co = wid * (MF * 16) + mf * 16 + q * 4 + r;
      if (CO != COp && co >= CO) continue;
      float bv = bias[co];
      #pragma unroll
      for (int nf = 0; nf < 4; ++nf){
        int pix = nf * 16 + l15;
        out[(size_t)(b * CO + co) * 2048 + h * 64 + pix] = acc[mf][nf][r] + bv;
      }
    }
  }
}

// ================= BN stats =================
struct GB { const float* g[5]; const float* b[5]; };

__global__ void __launch_bounds__(256) bn_stats1_k(const float* __restrict__ x, GB gb,
    float* __restrict__ A, float* __restrict__ Bv)
{
  int c = blockIdx.x;
  float s = 0.f, s2 = 0.f;
  for (int j = threadIdx.x; j < 16384; j += 256){
    int b = j >> 11, p = j & 2047;
    float v = x[(size_t)(b * 65 + c) * NPLANE + p];
    s += v; s2 += v * v;
  }
  s = blockRedN<0,4>(s);
  s2 = blockRedN<0,4>(s2);
  if (threadIdx.x == 0){
    float m = s * (1.0f / 16384.0f);
    float var = s2 * (1.0f / 16384.0f) - m * m;
    float rstd = rsqrtf(var + 1e-5f);
    int f = c / 13, k = c - f * 13;
    float g = gb.g[f][k], bb = gb.b[f][k];
    A[c] = g * rstd; Bv[c] = bb - m * g * rstd;
  }
}

__global__ void __launch_bounds__(64) prep_k(const float* __restrict__ hb,
  const float* __restrict__ A, const float* __restrict__ Bv,
  float* __restrict__ Fz, float* __restrict__ Fq, float* __restrict__ Fu,
  float* __restrict__ Fvf, float* __restrict__ Ft,
  float* __restrict__ zx, float* __restrict__ zy, float* __restrict__ zz,
  float* __restrict__ ux, float* __restrict__ vy, float* __restrict__ wv,
  float* __restrict__ part)
{
  int col = blockIdx.x * 64 + threadIdx.x;
  int b = col >> 11, p = col & 2047, h = p >> 6, w = p & 63;
  int hbase = b * 65 * NPLANE;
  auto hn = [&](int ch, int hh, int ww)->float {
    return hb[hbase + ch * NPLANE + hh * 64 + ww] * A[ch] + Bv[ch];
  };
  float zc[13], qc[13], uc[13], vc[13], tc[13];
  #pragma unroll
  for (int v = 0; v < 13; ++v){
    zc[v] = hn(v, h, w); qc[v] = hn(13 + v, h, w); uc[v] = hn(26 + v, h, w);
    vc[v] = hn(39 + v, h, w); tc[v] = hn(52 + v, h, w);
  }
  int fb = (b * 13) * 2048 + p;
  #pragma unroll
  for (int v = 0; v < 13; ++v){
    int fi = fb + v * 2048;
    Fz[fi] = zc[v]; Fq[fi] = qc[v]; Fu[fi] = uc[v]; Fvf[fi] = vc[v]; Ft[fi] = tc[v];
    zz[fi] = (-zc[pmv(v - 2)] + 8.f * zc[pmv(v - 1)] - 8.f * zc[pmv(v + 1)] + zc[pmv(v + 2)]) * (1.f / 12.f) / cDZ[v];
  }
  float lat = latOf(h);
  float invpx = 1.0f / (PXCc * cosf(lat));
  int wm2 = (w + 62) & 63, wm1 = (w + 63) & 63, wp1 = (w + 1) & 63, wp2 = (w + 2) & 63;
  int hm2 = pmh(h - 2), hm1 = pmh(h - 1), hp1 = pmh(h + 1), hp2 = pmh(h + 2);
  float cum = 0.f;
  #pragma unroll
  for (int v = 0; v < 13; ++v){
    int fi = fb + v * 2048;
    float zxv = (hn(v, h, wm2) - 8.f * hn(v, h, wm1) + 8.f * hn(v, h, wp1) - hn(v, h, wp2)) * (1.f / 12.f) * invpx;
    float zyv = (-hn(v, hm2, w) + 8.f * hn(v, hm1, w) - 8.f * hn(v, hp1, w) + hn(v, hp2, w)) * (1.f / 12.f) * (1.f / PYc);
    float uxv = (hn(26 + v, h, wm2) - 8.f * hn(26 + v, h, wm1) + 8.f * hn(26 + v, h, wp1) - hn(26 + v, h, wp2)) * (1.f / 12.f) * invpx;
    float vyv = (-hn(39 + v, hm2, w) + 8.f * hn(39 + v, hm1, w) - 8.f * hn(39 + v, hp1, w) + hn(39 + v, hp2, w)) * (1.f / 12.f) * (1.f / PYc);
    zx[fi] = zxv; zy[fi] = zyv; ux[fi] = uxv; vy[fi] = vyv;
    cum += cDZ[v] * (uxv + vyv);
    wv[fi] = -cum;
  }
  float smn = FBIG, smx = -FBIG;
  #pragma unroll
  for (int v = 0; v < 13; ++v){
    float tcc = tc[v] - 273.15f;
    float a = 17.67f * tcc / avoid_inf(tcc + 243.5f);
    smn = fminf(smn, a); smx = fmaxf(smx, a);
  }
  float fmn[5], fmx[5], fsm[5];
  #pragma unroll
  for (int f = 0; f < 5; ++f){
    const float* cc = f == 0 ? zc : f == 1 ? qc : f == 2 ? uc : f == 3 ? vc : tc;
    float mn = cc[0], mx = cc[0], sm = 0.f;
    #pragma unroll
    for (int v = 0; v < 13; ++v){ mn = fminf(mn, cc[v]); mx = fmaxf(mx, cc[v]); sm += cc[v]; }
    fmn[f] = mn; fmx[f] = mx; fsm[f] = sm;
  }
  float r;
  float* pb = part + blockIdx.x * 17;
  r = waveRedMin(smn); if (!threadIdx.x) pb[0] = r;
  r = waveRedMax(smx); if (!threadIdx.x) pb[1] = r;
  #pragma unroll
  for (int f = 0; f < 5; ++f){
    r = waveRedMin(fmn[f]); if (!threadIdx.x) pb[2 + f * 3] = r;
    r = waveRedMax(fmx[f]); if (!threadIdx.x) pb[3 + f * 3] = r;
    r = waveRedSum(fsm[f]); if (!threadIdx.x) pb[4 + f * 3] = r;
  }
}

// ===== merged RK stage: u,v,t (+C0/prr+sc1 at stage1, +q-tendency at stage2) =====
template<int STAGE>
__global__ void __launch_bounds__(256) stage_k(
  const float* U, const float* Vf, const float* T,
  const float* Fu, const float* Fvf, const float* Ft, const float* Fq,
  const float* ux, const float* vy, const float* zx, const float* zy,
  const float* wv, const float* zz, const float* partS,
  float* C0, float* prr,
  float* Uo, float* Vo, float* To,
  float* duA, float* dvA, float* dtA, float* k4t, float* qtA,
  float* pduv, float* pdt, float* pqt, float cnext)
{
  float ss = 0.f, off = 0.f;
  if (STAGE == 1){
    // redundant per-block finalize of saturation-arg scaling (256 partial rows)
    int tt = threadIdx.x;
    float smn = blockRedN<1,4>(partS[tt * 17]);
    float smx = blockRedN<2,4>(partS[tt * 17 + 1]);
    ss = (3.01f + 3.47f) / (smx - smn);
    off = -3.47f - smn * ss;
  }
  int i = blockIdx.x * 256 + threadIdx.x;
  int w = i & 63, h = (i >> 6) & 31;
  int bv = i >> 11;
  int v = bv % 13;
  int bvbase = bv * 2048;
  int rb = bvbase + h * 64;
  int bbase = (bv - v) * 2048;
  int hw = h * 64 + w;
  float lat = latOf(h);
  float invpx = 1.0f / (PXCc * cosf(lat));
  float fcor = 2.0f * OMEGAc * sinf(lat);
  float wvi = wv[i];
  float Ui = U[i], Vi = Vf[i], Ti = T[i];
  float Fui = (STAGE == 1) ? Ui : Fu[i];
  float Fvi = (STAGE == 1) ? Vi : Fvf[i];

  float dyU = d_yf(U, bvbase, h, w);
  float dzU = d_zf(U, bbase, v, hw);
  float dxV = d_xf(Vf, rb, w, invpx);
  float dzV = d_zf(Vf, bbase, v, hw);
  float mixU = KHc * (dxxf(U, rb, w, invpx) + dyyf(U, bvbase, h, w)) + KVc * dzzf(U, bbase, v, hw);
  float mixV = KHc * (dxxf(Vf, rb, w, invpx) + dyyf(Vf, bvbase, h, w)) + KVc * dzzf(Vf, bbase, v, hw);
  float ku = -Ui * ux[i] - Vi * dyU - wvi * dzU + fcor * Vi - zx[i] + mixU;
  float kv = -Ui * dxV - Vi * vy[i] - wvi * dzV - fcor * Ui - zy[i] + mixV;

  float C0i;
  if (STAGE == 1){
    float zzi = zz[i], qi = Fq[i];
    float rho = -1.0f / avoid_inf(zzi);
    float p = rho * R_GASc * Ti;               // Ti == Ft at stage 1
    float tcc = Ti - 273.15f;
    float arg = 17.67f * tcc / avoid_inf(tcc + 243.5f);
    float es = 6.112f * expf(arg * ss + off) * 100.0f;
    float qs = fmaxf(0.622f * es / avoid_inf(p - 0.378f * es), 1e-6f);
    float rh = qi / avoid_inf(qs);
    float rate = (rh > PTHc) ? (qi - PTHc * qs) * (1.0f / DT) : 0.0f;
    prr[i] = rate;
    C0i = -(L_Vc + 1.0f) * zzi * wvi * (1.0f / C_Pc) + rate * (L_Vc / C_Pc);
    C0[i] = C0i;
  } else {
    C0i = C0[i];
  }

  float dxT = d_xf(T, rb, w, invpx);
  float dyT = d_yf(T, bvbase, h, w);
  float dzT = d_zf(T, bbase, v, hw);
  float mixT = KHc * (dxxf(T, rb, w, invpx) + dyyf(T, bvbase, h, w)) + KVc * dzzf(T, bbase, v, hw);
  float ta = Ti + 273.15f;
  float t2 = ta * ta;
  float ta5 = t2 * t2 * ta;
  float rc = -RCCc * ta5 / cPRS[v];
  float kt = C0i - Fui * dxT - Fvi * dyT - wvi * dzT + mixT + rc;

  if (STAGE == 1){ duA[i] = ku; dvA[i] = kv; dtA[i] = kt; }
  else if (STAGE < 4){ duA[i] += 2.f * ku; dvA[i] += 2.f * kv; dtA[i] += 2.f * kt; }
  else {
    float au = duA[i] + ku, av = dvA[i] + kv, at = dtA[i] + kt;
    duA[i] = au; dvA[i] = av; dtA[i] = at; k4t[i] = kt;
    float m0 = blockRedN<1,4>(au), m1 = blockRedN<2,4>(au);
    float m2 = blockRedN<1,4>(av), m3 = blockRedN<2,4>(av);
    float m4 = blockRedN<1,4>(at), m5 = blockRedN<2,4>(at);
    if (!threadIdx.x){
      float* pp = pduv + blockIdx.x * 4;
      pp[0] = m0; pp[1] = m1; pp[2] = m2; pp[3] = m3;
      pdt[blockIdx.x * 2] = m4; pdt[blockIdx.x * 2 + 1] = m5;
    }
  }
  if (STAGE < 4){
    float Fti = (STAGE == 1) ? Ti : Ft[i];
    Uo[i] = Fui + cnext * ku;
    Vo[i] = Fvi + cnext * kv;
    To[i] = Fti + cnext * kt;
  }

  if (STAGE == 2){
    float qtv = -Fui * d_xf(Fq, rb, w, invpx) - Fvi * d_yf(Fq, bvbase, h, w) - wvi * d_zf(Fq, bbase, v, hw)
              + KHc * (dxxf(Fq, rb, w, invpx) + dyyf(Fq, bvbase, h, w)) + KVc * dzzf(Fq, bbase, v, hw) - prr[i];
    qtA[i] = qtv;
    float m0 = blockRedN<1,4>(qtv), m1 = blockRedN<2,4>(qtv);
    if (!threadIdx.x){ pqt[blockIdx.x * 2] = m0; pqt[blockIdx.x * 2 + 1] = m1; }
  }
}

__global__ void __launch_bounds__(64) zt_k(const float* __restrict__ k4t, float* __restrict__ zt, float* __restrict__ pmm)
{
  int col = blockIdx.x * 64 + threadIdx.x;
  int b = col >> 11, p = col & 2047;
  int fb = b * 13 * 2048 + p;
  float cum = 0.f, mn = FBIG, mx = -FBIG;
  #pragma unroll
  for (int v = 0; v < 13; ++v){
    cum += cDZ[v] * (-R_GASc / cPRS[v]) * k4t[fb + v * 2048];
    zt[fb + v * 2048] = cum;
    mn = fminf(mn, cum); mx = fmaxf(mx, cum);
  }
  mn = waveRedMin(mn); mx = waveRedMax(mx);
  if (!threadIdx.x){ pmm[blockIdx.x * 2] = mn; pmm[blockIdx.x * 2 + 1] = mx; }
}

// ===== fused: redundant sc2 finalize + outmid (LDS tile) + bf16 transpose out =====
__global__ void __launch_bounds__(256) outmid_fused_k(
  const float* __restrict__ hb,
  const float* __restrict__ Fz, const float* __restrict__ Fq, const float* __restrict__ Fu,
  const float* __restrict__ Fvf, const float* __restrict__ Ft,
  const float* __restrict__ ztA, const float* __restrict__ qtA,
  const float* __restrict__ duA, const float* __restrict__ dvA, const float* __restrict__ dtA,
  const float* __restrict__ coef, const float* __restrict__ partS,
  const float* __restrict__ pduv, const float* __restrict__ pdt,
  const float* __restrict__ pqt, const float* __restrict__ pzt,
  unsigned short* __restrict__ MT)
{
  __shared__ float tileBig[65 * 66];
  int blk = blockIdx.x, t = threadIdx.x;

  // --- redundant global-stat finalize ---
  const float* pr = partS + t * 17;
  float fmn[5], fmx[5], fsm[5];
  #pragma unroll
  for (int f = 0; f < 5; ++f){
    fmn[f] = blockRedN<1,4>(pr[2 + f * 3]);
    fmx[f] = blockRedN<2,4>(pr[3 + f * 3]);
    fsm[f] = blockRedN<0,4>(pr[4 + f * 3]);
  }
  float dumn = FBIG, dumx = -FBIG, dvmn = FBIG, dvmx = -FBIG, dtmn = FBIG, dtmx = -FBIG;
  float qmn = FBIG, qmx = -FBIG;
  #pragma unroll 1
  for (int r0 = t; r0 < 832; r0 += 256){
    dumn = fminf(dumn, pduv[r0 * 4]);     dumx = fmaxf(dumx, pduv[r0 * 4 + 1]);
    dvmn = fminf(dvmn, pduv[r0 * 4 + 2]); dvmx = fmaxf(dvmx, pduv[r0 * 4 + 3]);
    dtmn = fminf(dtmn, pdt[r0 * 2]);      dtmx = fmaxf(dtmx, pdt[r0 * 2 + 1]);
    qmn = fminf(qmn, pqt[r0 * 2]);        qmx = fmaxf(qmx, pqt[r0 * 2 + 1]);
  }
  float zmn = pzt[t * 2], zmx = pzt[t * 2 + 1];
  dumn = blockRedN<1,4>(dumn); dumx = blockRedN<2,4>(dumx);
  dvmn = blockRedN<1,4>(dvmn); dvmx = blockRedN<2,4>(dvmx);
  dtmn = blockRedN<1,4>(dtmn); dtmx = blockRedN<2,4>(dtmx);
  qmn = blockRedN<1,4>(qmn);   qmx = blockRedN<2,4>(qmx);
  zmn = blockRedN<1,4>(zmn);   zmx = blockRedN<2,4>(zmx);

  float scf[5], off2[5];
  {
    float rmn[5] = {zmn, qmn, dumn, dvmn, dtmn};
    float rmx[5] = {zmx, qmx, dumx, dvmx, dtmx};
    float cfs[5] = {DT, DT, DT / 6.f, DT / 6.f, DT / 6.f};
    #pragma unroll
    for (int f = 0; f < 5; ++f){
      float mnf = fmn[f], mef = fsm[f] * (1.0f / (float)NF), mxf = fmx[f];
      float aa = (mnf - mef) * 0.05f, b2 = (mxf - mef) * 0.05f;
      float cf = cfs[f];
      float dmn = rmn[f] * cf, dmx = rmx[f] * cf;
      float s = (b2 - aa) / (dmx - dmn);
      scf[f] = s * cf; off2[f] = aa - dmn * s;
    }
  }

  // --- mid tile for this (b,h) slice ---
  int b = blk >> 5, h = blk & 31;
  #pragma unroll 1
  for (int idx = t; idx < 65 * 64; idx += 256){
    int c = idx >> 6, w = idx & 63;
    int f = c / 13, v = c - f * 13;
    int fi = (b * 13 + v) * 2048 + h * 64 + w;
    const float *Fp, *Rp;
    switch (f){
      case 0: Fp = Fz;  Rp = ztA; break;
      case 1: Fp = Fq;  Rp = qtA; break;
      case 2: Fp = Fu;  Rp = duA; break;
      case 3: Fp = Fvf; Rp = dvA; break;
      default: Fp = Ft; Rp = dtA; break;
    }
    float phys = Fp[fi] + Rp[fi] * scf[f] + off2[f];
    float cf = coef[c * 2048 + h * 64 + w];
    float hbv = hb[((size_t)(b * 65 + c)) * 2048 + h * 64 + w];
    tileBig[c * 66 + w] = cf * phys + (1.0f - cf) * hbv;
  }
  __syncthreads();
  // --- transpose to MT bf16 [b][h][w][96] ---
  #pragma unroll 1
  for (int ph = 0; ph < 6; ++ph){
    int cbase = ph * 16;
    int w = t >> 2, c4 = (t & 3) * 4;
    int c0 = cbase + c4;
    ushort4 o;
    o.x = (c0 + 0 < 65) ? f2bf(tileBig[(c0 + 0) * 66 + w]) : (unsigned short)0;
    o.y = (c0 + 1 < 65) ? f2bf(tileBig[(c0 + 1) * 66 + w]) : (unsigned short)0;
    o.z = (c0 + 2 < 65) ? f2bf(tileBig[(c0 + 2) * 66 + w]) : (unsigned short)0;
    o.w = (c0 + 3 < 65) ? f2bf(tileBig[(c0 + 3) * 66 + w]) : (unsigned short)0;
    *(ushort4*)(MT + (((size_t)(b * 32 + h) * 64 + w) * 96 + c0)) = o;
  }
}

__global__ void __launch_bounds__(256) bn_stats2_k(const float* __restrict__ y,
  const float* __restrict__ g, const float* __restrict__ bb, float* __restrict__ A, float* __restrict__ Bv)
{
  int c = blockIdx.x;
  float s = 0.f, s2 = 0.f;
  for (int j = threadIdx.x; j < 16384; j += 256){
    int b = j >> 11, p = j & 2047;
    float v = y[(size_t)(b * 256 + c) * 2048 + p];
    s += v; s2 += v * v;
  }
  s = blockRedN<0,4>(s);
  s2 = blockRedN<0,4>(s2);
  if (!threadIdx.x){
    float m = s * (1.0f / 16384.0f);
    float var = s2 * (1.0f / 16384.0f) - m * m;
    float rstd = rsqrtf(var + 1e-5f);
    A[c] = g[c] * rstd; Bv[c] = bb[c] - m * g[c] * rstd;
  }
}

__global__ void __launch_bounds__(256) final_k(float* __restrict__ y, const float* __restrict__ x,
  const float* __restrict__ A, const float* __restrict__ Bv)
{
  int e4 = blockIdx.x * 256 + threadIdx.x;
  int c = (e4 >> 9) & 255;
  float4 v = ((const float4*)y)[e4];
  float4 xv = ((const float4*)x)[e4];
  float a = A[c], bb = Bv[c];
  v.x = v.x * a + bb + xv.x;
  v.y = v.y * a + bb + xv.y;
  v.z = v.z * a + bb + xv.z;
  v.w = v.w * a + bb + xv.w;
  ((float4*)y)[e4] = v;
}

extern "C" void kernel_launch(void* const* d_in, const int* in_sizes, int n_in,
                              void* d_out, int out_size, void* d_ws, size_t ws_size,
                              hipStream_t stream)
{
  (void)in_sizes; (void)n_in; (void)out_size; (void)ws_size;
  const float* x        = (const float*)d_in[0];
  const float* w_norm   = (const float*)d_in[1];
  const float* b_norm   = (const float*)d_in[2];
  const float* w_innorm = (const float*)d_in[3];
  const float* b_innorm = (const float*)d_in[4];
  const float* coef     = (const float*)d_in[5];
  GB gb;
  for (int f = 0; f < 5; ++f){
    gb.g[f] = (const float*)d_in[6 + 2 * f];
    gb.b[f] = (const float*)d_in[7 + 2 * f];
  }
  const float* gblk = (const float*)d_in[16];
  const float* bblk = (const float*)d_in[17];
  float* yout = (float*)d_out;

  float* ws = (float*)d_ws;
  size_t off = 0;
  auto alloc = [&](size_t n){ float* p = ws + off; off += n; return p; };
  float* hb  = alloc(NHB);
  float* Fz  = alloc(NF); float* Fq  = alloc(NF); float* Fu  = alloc(NF);
  float* Fvf = alloc(NF); float* Ft  = alloc(NF);
  float* zx  = alloc(NF); float* zy  = alloc(NF); float* zz  = alloc(NF);
  float* ux  = alloc(NF); float* vy  = alloc(NF); float* wvel = alloc(NF);
  float* C0  = alloc(NF); float* prr = alloc(NF);
  float* Ua  = alloc(NF); float* Ub  = alloc(NF); float* Va  = alloc(NF); float* Vb = alloc(NF);
  float* Ta  = alloc(NF); float* Tb  = alloc(NF);
  float* duA = alloc(NF); float* dvA = alloc(NF); float* dtA = alloc(NF);
  float* k4t = alloc(NF); float* ztA = alloc(NF); float* qtA = alloc(NF);
  float* A1 = alloc(65);  float* B1 = alloc(65);
  float* A2 = alloc(256); float* B2 = alloc(256);
  float* part1 = alloc(256 * 17);
  float* pduv = alloc(832 * 4); float* pdt = alloc(832 * 2);
  float* pqt  = alloc(832 * 2); float* pzt = alloc(256 * 2);
  float* Wp1f = alloc(9 * 80 * 256 / 2);   // bf16 [9][80][256]
  float* Wp2f = alloc(9 * 256 * 96 / 2);   // bf16 [9][256][96]
  unsigned short* Wp1 = (unsigned short*)Wp1f;
  unsigned short* Wp2 = (unsigned short*)Wp2f;
  // XT bf16 [8][32][64][256] (8 MB) aliases Ua..k4t (10*NF*4 = 8.5 MB); dead after conv1,
  // long before stage1 writes Ua.
  unsigned short* XT = (unsigned short*)Ua;
  // MT bf16 [8][32][64][96] (3.15 MB) aliases C0,prr,Ua,Ub (4*NF*4 = 3.4 MB) — all dead
  // after stage4; outmid reads NONE of them (reads Fz..Ft, ztA, qtA, duA/dvA/dtA, hb).
  unsigned short* MT = (unsigned short*)C0;

  // 1. transpose x + pack both weights
  pre_k<<<2608, 256, 0, stream>>>(x, w_norm, w_innorm, XT, Wp1, Wp2);
  // 2. conv1 (bf16 MFMA implicit GEMM)
  conv_mfma_k<256, 128, 65, 80, 5, 1, 7><<<dim3(32, 8), 5 * 64, 0, stream>>>(XT, Wp1, b_norm, hb);
  // 3. BN1 stats
  bn_stats1_k<<<65, 256, 0, stream>>>(hb, gb, A1, B1);
  // 4. prep (+ sc1/field-stat partials)
  prep_k<<<NCOL / 64, 64, 0, stream>>>(hb, A1, B1, Fz, Fq, Fu, Fvf, Ft, zx, zy, zz, ux, vy, wvel, part1);
  // 5-8. RK stages (stage1 redundantly finalizes sc1; stage2 adds q-tendency)
  stage_k<1><<<NF / 256, 256, 0, stream>>>(Fu, Fvf, Ft, Fu, Fvf, Ft, Fq, ux, vy, zx, zy, wvel, zz, part1,
      C0, prr, Ua, Va, Ta, duA, dvA, dtA, k4t, qtA, pduv, pdt, pqt, 0.5f * DT);
  stage_k<2><<<NF / 256, 256, 0, stream>>>(Ua, Va, Ta, Fu, Fvf, Ft, Fq, ux, vy, zx, zy, wvel, zz, part1,
      C0, prr, Ub, Vb, Tb, duA, dvA, dtA, k4t, qtA, pduv, pdt, pqt, 0.5f * DT);
  stage_k<3><<<NF / 256, 256, 0, stream>>>(Ub, Vb, Tb, Fu, Fvf, Ft, Fq, ux, vy, zx, zy, wvel, zz, part1,
      C0, prr, Ua, Va, Ta, duA, dvA, dtA, k4t, qtA, pduv, pdt, pqt, DT);
  stage_k<4><<<NF / 256, 256, 0, stream>>>(Ua, Va, Ta, Fu, Fvf, Ft, Fq, ux, vy, zx, zy, wvel, zz, part1,
      C0, prr, Ub, Vb, Tb, duA, dvA, dtA, k4t, qtA, pduv, pdt, pqt, 0.f);
  // 9. z-tendency integral
  zt_k<<<NCOL / 64, 64, 0, stream>>>(k4t, ztA, pzt);
  // 10. fused finalize2 + outmid + bf16 transpose
  outmid_fused_k<<<256, 256, 0, stream>>>(hb, Fz, Fq, Fu, Fvf, Ft, ztA, qtA, duA, dvA, dtA,
      coef, part1, pduv, pdt, pqt, pzt, MT);
  // 11. conv2
  conv_mfma_k<96, 96, 256, 256, 8, 2, 3><<<dim3(32, 8), 8 * 64, 0, stream>>>(MT, Wp2, b_innorm, yout);
  // 12. BN2 stats
  bn_stats2_k<<<256, 256, 0, stream>>>(yout, gblk, bblk, A2, B2);
  // 13. apply BN + residual
  final_k<<<4194304 / 4 / 256, 256, 0, stream>>>(yout, x, A2, B2);
}

// Round 7
// 181.249 us; speedup vs baseline: 8.1814x; 1.1773x over previous
//
#include <hip/hip_runtime.h>
#include <math.h>

#define DEVFN static __device__ __forceinline__

static constexpr int BB = 8, VV = 13, HH = 32, WW = 64;
static constexpr int NPLANE = HH * WW;        // 2048
static constexpr int NF = BB * VV * NPLANE;   // 212992
static constexpr int NHB = BB * 65 * NPLANE;  // 1064960

static constexpr float DT = 300.0f;
static constexpr float KHc = 15.0f, KVc = 0.1f;
static constexpr float OMEGAc = 7.29e-5f;
static constexpr float L_Vc = 2.5e6f;
static constexpr float R_GASc = 8.314f;
static constexpr float C_Pc = 1005.0f;
static constexpr float PTHc = 0.8f;
static constexpr float PYc  = (float)(3.14159265358979323846 * 6371000.0 / 33.0);
static constexpr float PXCc = (float)(2.0 * 3.14159265358979323846 * 6371000.0 / 64.0);
static constexpr float RCCc = (float)(0.7 * 5.67e-8 * 287.0 / (1005.0 * 100.0));
static constexpr float FBIG = 3.402823466e38f;

__constant__ float cDZ[13]  = {50,50,50,50,50,75,100,100,100,125,112,75,75};
__constant__ float cPRS[13] = {50,100,150,200,250,300,400,500,600,700,850,925,1000};

typedef short bf16x8 __attribute__((ext_vector_type(8)));
typedef float f32x4 __attribute__((ext_vector_type(4)));

DEVFN int pmh(int r){ return r < 0 ? r + 2 : (r > HH - 1 ? r - 2 : r); }
DEVFN int pmv(int r){ return r < 0 ? r + 2 : (r > VV - 1 ? r - 2 : r); }
DEVFN float latOf(int h){ return (90.0f - (float)(h + 1) * (180.0f / 33.0f)) * 0.017453292519943295f; }
DEVFN float avoid_inf(float t){
  if (t == 0.0f) t = 0.1f;
  if (fabsf(t) < 1.0f) t = copysignf(1.0f, t);
  return t;
}
DEVFN unsigned short f2bf(float f){
  unsigned u = __float_as_uint(f);
  unsigned r = (u + 0x7fffu + ((u >> 16) & 1u)) >> 16;
  return (unsigned short)r;
}

// ---- stencils on [B][13][32][64] ----
DEVFN float d_xf(const float* __restrict__ F, int rb, int w, float invpx){
  return (F[rb + ((w + 62) & 63)] - 8.f * F[rb + ((w + 63) & 63)]
        + 8.f * F[rb + ((w + 1) & 63)] - F[rb + ((w + 2) & 63)]) * (1.f / 12.f) * invpx;
}
DEVFN float d_yf(const float* __restrict__ F, int bvbase, int h, int w){
  return (-F[bvbase + pmh(h - 2) * 64 + w] + 8.f * F[bvbase + pmh(h - 1) * 64 + w]
          - 8.f * F[bvbase + pmh(h + 1) * 64 + w] + F[bvbase + pmh(h + 2) * 64 + w]) * (1.f / 12.f) * (1.f / PYc);
}
DEVFN float d_zf(const float* __restrict__ F, int bbase, int v, int hw){
  return (-F[bbase + pmv(v - 2) * 2048 + hw] + 8.f * F[bbase + pmv(v - 1) * 2048 + hw]
          - 8.f * F[bbase + pmv(v + 1) * 2048 + hw] + F[bbase + pmv(v + 2) * 2048 + hw]) * (1.f / 12.f) / cDZ[v];
}
DEVFN float dxxf(const float* __restrict__ F, int rb, int w, float invpx){
  float s = F[rb + ((w + 60) & 63)] - 16.f * F[rb + ((w + 61) & 63)] + 64.f * F[rb + ((w + 62) & 63)]
          + 16.f * F[rb + ((w + 63) & 63)] - 130.f * F[rb + w] + 16.f * F[rb + ((w + 1) & 63)]
          + 64.f * F[rb + ((w + 2) & 63)] - 16.f * F[rb + ((w + 3) & 63)] + F[rb + ((w + 4) & 63)];
  return s * (1.f / 144.f) * invpx * invpx;
}
DEVFN float dyyf(const float* __restrict__ F, int bvbase, int h, int w){
  float g0 = d_yf(F, bvbase, pmh(h - 2), w);
  float g1 = d_yf(F, bvbase, pmh(h - 1), w);
  float g2 = d_yf(F, bvbase, pmh(h + 1), w);
  float g3 = d_yf(F, bvbase, pmh(h + 2), w);
  return (-g0 + 8.f * g1 - 8.f * g2 + g3) * (1.f / 12.f) * (1.f / PYc);
}
DEVFN float dzzf(const float* __restrict__ F, int bbase, int v, int hw){
  float g0 = d_zf(F, bbase, pmv(v - 2), hw);
  float g1 = d_zf(F, bbase, pmv(v - 1), hw);
  float g2 = d_zf(F, bbase, pmv(v + 1), hw);
  float g3 = d_zf(F, bbase, pmv(v + 2), hw);
  return (-g0 + 8.f * g1 - 8.f * g2 + g3) * (1.f / 12.f) / cDZ[v];
}

// ---- reductions ----
DEVFN float waveRedSum(float v){ for (int o = 32; o; o >>= 1) v += __shfl_down(v, o, 64); return v; }
DEVFN float waveRedMin(float v){ for (int o = 32; o; o >>= 1) v = fminf(v, __shfl_down(v, o, 64)); return v; }
DEVFN float waveRedMax(float v){ for (int o = 32; o; o >>= 1) v = fmaxf(v, __shfl_down(v, o, 64)); return v; }

template<int OP, int NWV>
static __device__ float blockRedN(float v){
  __shared__ float s[NWV];
  v = OP == 0 ? waveRedSum(v) : OP == 1 ? waveRedMin(v) : waveRedMax(v);
  int lane = threadIdx.x & 63, wid = threadIdx.x >> 6;
  __syncthreads();
  if (lane == 0) s[wid] = v;
  __syncthreads();
  float r = s[0];
  #pragma unroll
  for (int k = 1; k < NWV; ++k)
    r = OP == 0 ? r + s[k] : OP == 1 ? fminf(r, s[k]) : fmaxf(r, s[k]);
  return r;
}

struct GB { const float* g[5]; const float* b[5]; };

// ================= launch 1: transpose x + pack both weights =================
__global__ void __launch_bounds__(256) pre_k(const float* __restrict__ x,
    const float* __restrict__ w1, const float* __restrict__ w2,
    unsigned short* __restrict__ XT, unsigned short* __restrict__ wp1,
    unsigned short* __restrict__ wp2)
{
  int blk = blockIdx.x, t = threadIdx.x;
  if (blk < 1024){
    __shared__ float tile[16 * 68];
    int zz = blk >> 8, rem = blk & 255;
    int b = rem >> 5, h = rem & 31;
    for (int p = zz * 4; p < zz * 4 + 4; ++p){
      int cbase = p * 16;
      __syncthreads();
      {
        int cl = t >> 4, w4 = (t & 15) * 4;
        float4 v = *(const float4*)(x + (((size_t)(b * 256 + cbase + cl) * 32 + h) * 64 + w4));
        tile[cl * 68 + w4 + 0] = v.x; tile[cl * 68 + w4 + 1] = v.y;
        tile[cl * 68 + w4 + 2] = v.z; tile[cl * 68 + w4 + 3] = v.w;
      }
      __syncthreads();
      {
        int w = t >> 2, c4 = (t & 3) * 4;
        ushort4 o;
        o.x = f2bf(tile[(c4 + 0) * 68 + w]);
        o.y = f2bf(tile[(c4 + 1) * 68 + w]);
        o.z = f2bf(tile[(c4 + 2) * 68 + w]);
        o.w = f2bf(tile[(c4 + 3) * 68 + w]);
        *(ushort4*)(XT + (((size_t)(b * 32 + h) * 64 + w) * 256 + cbase + c4)) = o;
      }
    }
  } else {
    const int T1 = 9 * 80 * 256;
    const int T2 = 9 * 256 * 96;
    int idx = (blk - 1024) * 256 + t;
    if (idx < T1){
      int dir = idx / (80 * 256);
      int r = idx - dir * (80 * 256);
      int co = r / 256, ci = r - co * 256;
      float v = (co < 65) ? w1[((size_t)(co * 256 + ci)) * 9 + dir] : 0.f;
      wp1[idx] = f2bf(v);
    } else if (idx < T1 + T2){
      int j = idx - T1;
      int dir = j / (256 * 96);
      int r = j - dir * (256 * 96);
      int co = r / 96, ci = r - co * 96;
      float v = (ci < 65) ? w2[((size_t)(co * 65 + ci)) * 9 + dir] : 0.f;
      wp2[j] = f2bf(v);
    }
  }
}

// ================= conv via MFMA; 32-pixel blocks; BN partials in epilogue =================
// grid (64, 8): bx -> h = bx>>1, half = bx&1. bnp layout [ch][512][2].
template<int CIT, int CIL, int CO, int COp, int NW, int MF, int SWZ>
__global__ void __launch_bounds__(NW * 64) conv_mfma_k(
    const unsigned short* __restrict__ XT, const unsigned short* __restrict__ Wp,
    const float* __restrict__ bias, float* __restrict__ out, float* __restrict__ bnp)
{
  __shared__ __align__(16) unsigned short Xl[3 * 34 * CIL];
  const int C8 = CIL / 8;
  int tid = threadIdx.x;
  int bx = blockIdx.x, b = blockIdx.y;
  int h = bx >> 1, p0 = (bx & 1) << 5;
  int bh = b * 64 + bx;
  int wid = tid >> 6, lane = tid & 63;
  int l15 = lane & 15, q = lane >> 4;

  f32x4 acc[MF][2];
  #pragma unroll
  for (int mf = 0; mf < MF; ++mf)
    #pragma unroll
    for (int nf = 0; nf < 2; ++nf){ f32x4 z = {0.f, 0.f, 0.f, 0.f}; acc[mf][nf] = z; }

  for (int cp = 0; cp < CIT / CIL; ++cp){
    if (cp) __syncthreads();
    for (int idx = tid; idx < 3 * 34 * C8; idx += NW * 64){
      int r = idx / (34 * C8);
      int rest = idx - r * (34 * C8);
      int j = rest / C8;
      int c8 = rest - j * C8;
      int hh = h + r - 1;
      int gw = p0 - 1 + j;
      uint4 val = make_uint4(0, 0, 0, 0);
      if (hh >= 0 && hh < 32 && gw >= 0 && gw < 64)
        val = *(const uint4*)(XT + (((size_t)(b * 32 + hh) * 64 + gw) * CIT + cp * CIL + c8 * 8));
      int dst = (r * 34 + j) * CIL + ((c8 * 8) ^ ((j & SWZ) << 3));
      *(uint4*)(Xl + dst) = val;
    }
    __syncthreads();

    for (int dir = 0; dir < 9; ++dir){
      int dy = dir / 3, dx = dir - dy * 3;
      #pragma unroll
      for (int kc = 0; kc < CIL / 32; ++kc){
        int kb = kc * 32 + q * 8;
        bf16x8 a[MF];
        #pragma unroll
        for (int mf = 0; mf < MF; ++mf){
          int co = wid * (MF * 16) + mf * 16 + l15;
          a[mf] = *(const bf16x8*)(Wp + ((size_t)(dir * COp + co) * CIT + cp * CIL + kb));
        }
        #pragma unroll
        for (int nf = 0; nf < 2; ++nf){
          int j = nf * 16 + l15 + dx;
          bf16x8 bfrag = *(const bf16x8*)(Xl + ((dy * 34 + j) * CIL + (kb ^ ((j & SWZ) << 3))));
          #pragma unroll
          for (int mf = 0; mf < MF; ++mf)
            acc[mf][nf] = __builtin_amdgcn_mfma_f32_16x16x32_bf16(a[mf], bfrag, acc[mf][nf], 0, 0, 0);
        }
      }
    }
  }
  // store + per-block per-channel BN partial sums (over this block's 32 pixels)
  #pragma unroll
  for (int mf = 0; mf < MF; ++mf){
    #pragma unroll
    for (int r = 0; r < 4; ++r){
      int co = wid * (MF * 16) + mf * 16 + q * 4 + r;
      if (CO != COp && co >= CO) continue;
      float bv = bias[co];
      float sv = 0.f, sq = 0.f;
      #pragma unroll
      for (int nf = 0; nf < 2; ++nf){
        int pix = nf * 16 + l15;
        float val = acc[mf][nf][r] + bv;
        out[(size_t)(b * CO + co) * 2048 + h * 64 + p0 + pix] = val;
        sv += val; sq += val * val;
      }
      #pragma unroll
      for (int off = 8; off; off >>= 1){
        sv += __shfl_xor(sv, off, 16);
        sq += __shfl_xor(sq, off, 16);
      }
      if (l15 == 0){
        bnp[((size_t)co * 512 + bh) * 2]     = sv;
        bnp[((size_t)co * 512 + bh) * 2 + 1] = sq;
      }
    }
  }
}

// ================= prep: BN1 finalize (redundant) + field prep, 6-way split =================
__global__ void __launch_bounds__(256) prep_k(const float* __restrict__ hb,
  const float* __restrict__ bnp1, GB gb,
  float* __restrict__ Fz, float* __restrict__ Fq, float* __restrict__ Fu,
  float* __restrict__ Fvf, float* __restrict__ Ft,
  float* __restrict__ zx, float* __restrict__ zy, float* __restrict__ zz,
  float* __restrict__ ux, float* __restrict__ vy, float* __restrict__ wv,
  float* __restrict__ partS)
{
  __shared__ float As[65], Bs[65];
  int blk = blockIdx.x, t = threadIdx.x;
  {
    int wvid = t >> 6, lane = t & 63;
    for (int ch = wvid; ch < 65; ch += 4){
      const float4* pp = (const float4*)(bnp1 + (size_t)ch * 1024) + lane * 4;
      float s = 0.f, sq = 0.f;
      #pragma unroll
      for (int k = 0; k < 4; ++k){ float4 v = pp[k]; s += v.x + v.z; sq += v.y + v.w; }
      s = waveRedSum(s); sq = waveRedSum(sq);
      if (!lane){
        float m = s * (1.f / 16384.f);
        float var = sq * (1.f / 16384.f) - m * m;
        float rstd = rsqrtf(var + 1e-5f);
        int f = ch / 13, k = ch - f * 13;
        float g = gb.g[f][k], bbv = gb.b[f][k];
        As[ch] = g * rstd; Bs[ch] = bbv - m * g * rstd;
      }
    }
  }
  __syncthreads();

  int part = blk >> 6;
  int col = ((blk & 63) << 8) | t;
  int b = col >> 11, p = col & 2047, h = p >> 6, w = p & 63;
  int hbase = b * 65 * NPLANE;
  auto hn = [&](int ch, int hh, int ww)->float {
    return hb[hbase + ch * 2048 + hh * 64 + ww] * As[ch] + Bs[ch];
  };
  int fb = (b * 13) * 2048 + p;
  float lat = latOf(h);
  float invpx = 1.0f / (PXCc * cosf(lat));
  int wm2 = (w + 62) & 63, wm1 = (w + 63) & 63, wpl1 = (w + 1) & 63, wpl2 = (w + 2) & 63;
  int hm2 = pmh(h - 2), hm1 = pmh(h - 1), hp1 = pmh(h + 1), hp2 = pmh(h + 2);
  float fmn = FBIG, fmx = -FBIG, fsm = 0.f, smn = FBIG, smx = -FBIG;
  if (part < 5){
    int ch0 = part * 13;
    float c[13];
    #pragma unroll
    for (int v = 0; v < 13; ++v) c[v] = hn(ch0 + v, h, w);
    float* Fdst = part == 0 ? Fz : part == 1 ? Fq : part == 2 ? Fu : part == 3 ? Fvf : Ft;
    #pragma unroll
    for (int v = 0; v < 13; ++v) Fdst[fb + v * 2048] = c[v];
    if (part == 0){
      #pragma unroll
      for (int v = 0; v < 13; ++v){
        zz[fb + v * 2048] = (-c[pmv(v - 2)] + 8.f * c[pmv(v - 1)] - 8.f * c[pmv(v + 1)] + c[pmv(v + 2)]) * (1.f / 12.f) / cDZ[v];
        float zxv = (hn(v, h, wm2) - 8.f * hn(v, h, wm1) + 8.f * hn(v, h, wpl1) - hn(v, h, wpl2)) * (1.f / 12.f) * invpx;
        float zyv = (-hn(v, hm2, w) + 8.f * hn(v, hm1, w) - 8.f * hn(v, hp1, w) + hn(v, hp2, w)) * (1.f / 12.f) * (1.f / PYc);
        zx[fb + v * 2048] = zxv; zy[fb + v * 2048] = zyv;
      }
    }
    if (part == 2){
      #pragma unroll
      for (int v = 0; v < 13; ++v){
        float uxv = (hn(26 + v, h, wm2) - 8.f * hn(26 + v, h, wm1) + 8.f * hn(26 + v, h, wpl1) - hn(26 + v, h, wpl2)) * (1.f / 12.f) * invpx;
        ux[fb + v * 2048] = uxv;
      }
    }
    if (part == 3){
      #pragma unroll
      for (int v = 0; v < 13; ++v){
        float vyv = (-hn(39 + v, hm2, w) + 8.f * hn(39 + v, hm1, w) - 8.f * hn(39 + v, hp1, w) + hn(39 + v, hp2, w)) * (1.f / 12.f) * (1.f / PYc);
        vy[fb + v * 2048] = vyv;
      }
    }
    if (part == 4){
      #pragma unroll
      for (int v = 0; v < 13; ++v){
        float tcc = c[v] - 273.15f;
        float arg = 17.67f * tcc / avoid_inf(tcc + 243.5f);
        smn = fminf(smn, arg); smx = fmaxf(smx, arg);
      }
    }
    #pragma unroll
    for (int v = 0; v < 13; ++v){ fmn = fminf(fmn, c[v]); fmx = fmaxf(fmx, c[v]); fsm += c[v]; }
  } else {
    float cum = 0.f;
    #pragma unroll
    for (int v = 0; v < 13; ++v){
      float uxv = (hn(26 + v, h, wm2) - 8.f * hn(26 + v, h, wm1) + 8.f * hn(26 + v, h, wpl1) - hn(26 + v, h, wpl2)) * (1.f / 12.f) * invpx;
      float vyv = (-hn(39 + v, hm2, w) + 8.f * hn(39 + v, hm1, w) - 8.f * hn(39 + v, hp1, w) + hn(39 + v, hp2, w)) * (1.f / 12.f) * (1.f / PYc);
      cum += cDZ[v] * (uxv + vyv);
      wv[fb + v * 2048] = -cum;
    }
  }
  float* pb = partS + blk * 17;
  float r;
  r = blockRedN<1,4>(smn); if (!t) pb[0] = r;
  r = blockRedN<2,4>(smx); if (!t) pb[1] = r;
  #pragma unroll
  for (int f = 0; f < 5; ++f){
    r = blockRedN<1,4>(part == f ? fmn : FBIG);  if (!t) pb[2 + f * 3] = r;
    r = blockRedN<2,4>(part == f ? fmx : -FBIG); if (!t) pb[3 + f * 3] = r;
    r = blockRedN<0,4>(part == f ? fsm : 0.f);   if (!t) pb[4 + f * 3] = r;
  }
}

// ===== merged RK stage: u,v,t (+C0/prr+sc1 at stage1, +q-tendency at stage2) =====
template<int STAGE>
__global__ void __launch_bounds__(256) stage_k(
  const float* U, const float* Vf, const float* T,
  const float* Fu, const float* Fvf, const float* Ft, const float* Fq,
  const float* ux, const float* vy, const float* zx, const float* zy,
  const float* wv, const float* zz, const float* partS,
  float* C0, float* prr,
  float* Uo, float* Vo, float* To,
  float* duA, float* dvA, float* dtA, float* k4t, float* qtA,
  float* pduv, float* pdt, float* pqt, float cnext)
{
  float ss = 0.f, off = 0.f;
  if (STAGE == 1){
    int tt = threadIdx.x;
    float v0 = partS[tt * 17], v1 = partS[tt * 17 + 1];
    if (tt < 128){
      v0 = fminf(v0, partS[(tt + 256) * 17]);
      v1 = fmaxf(v1, partS[(tt + 256) * 17 + 1]);
    }
    float smn = blockRedN<1,4>(v0);
    float smx = blockRedN<2,4>(v1);
    ss = (3.01f + 3.47f) / (smx - smn);
    off = -3.47f - smn * ss;
  }
  int i = blockIdx.x * 256 + threadIdx.x;
  int w = i & 63, h = (i >> 6) & 31;
  int bv = i >> 11;
  int v = bv % 13;
  int bvbase = bv * 2048;
  int rb = bvbase + h * 64;
  int bbase = (bv - v) * 2048;
  int hw = h * 64 + w;
  float lat = latOf(h);
  float invpx = 1.0f / (PXCc * cosf(lat));
  float fcor = 2.0f * OMEGAc * sinf(lat);
  float wvi = wv[i];
  float Ui = U[i], Vi = Vf[i], Ti = T[i];
  float Fui = (STAGE == 1) ? Ui : Fu[i];
  float Fvi = (STAGE == 1) ? Vi : Fvf[i];

  float dyU = d_yf(U, bvbase, h, w);
  float dzU = d_zf(U, bbase, v, hw);
  float dxV = d_xf(Vf, rb, w, invpx);
  float dzV = d_zf(Vf, bbase, v, hw);
  float mixU = KHc * (dxxf(U, rb, w, invpx) + dyyf(U, bvbase, h, w)) + KVc * dzzf(U, bbase, v, hw);
  float mixV = KHc * (dxxf(Vf, rb, w, invpx) + dyyf(Vf, bvbase, h, w)) + KVc * dzzf(Vf, bbase, v, hw);
  float ku = -Ui * ux[i] - Vi * dyU - wvi * dzU + fcor * Vi - zx[i] + mixU;
  float kv = -Ui * dxV - Vi * vy[i] - wvi * dzV - fcor * Ui - zy[i] + mixV;

  float C0i;
  if (STAGE == 1){
    float zzi = zz[i], qi = Fq[i];
    float rho = -1.0f / avoid_inf(zzi);
    float p = rho * R_GASc * Ti;
    float tcc = Ti - 273.15f;
    float arg = 17.67f * tcc / avoid_inf(tcc + 243.5f);
    float es = 6.112f * expf(arg * ss + off) * 100.0f;
    float qs = fmaxf(0.622f * es / avoid_inf(p - 0.378f * es), 1e-6f);
    float rh = qi / avoid_inf(qs);
    float rate = (rh > PTHc) ? (qi - PTHc * qs) * (1.0f / DT) : 0.0f;
    prr[i] = rate;
    C0i = -(L_Vc + 1.0f) * zzi * wvi * (1.0f / C_Pc) + rate * (L_Vc / C_Pc);
    C0[i] = C0i;
  } else {
    C0i = C0[i];
  }

  float dxT = d_xf(T, rb, w, invpx);
  float dyT = d_yf(T, bvbase, h, w);
  float dzT = d_zf(T, bbase, v, hw);
  float mixT = KHc * (dxxf(T, rb, w, invpx) + dyyf(T, bvbase, h, w)) + KVc * dzzf(T, bbase, v, hw);
  float ta = Ti + 273.15f;
  float t2 = ta * ta;
  float ta5 = t2 * t2 * ta;
  float rc = -RCCc * ta5 / cPRS[v];
  float kt = C0i - Fui * dxT - Fvi * dyT - wvi * dzT + mixT + rc;

  if (STAGE == 1){ duA[i] = ku; dvA[i] = kv; dtA[i] = kt; }
  else if (STAGE < 4){ duA[i] += 2.f * ku; dvA[i] += 2.f * kv; dtA[i] += 2.f * kt; }
  else {
    float au = duA[i] + ku, av = dvA[i] + kv, at = dtA[i] + kt;
    duA[i] = au; dvA[i] = av; dtA[i] = at; k4t[i] = kt;
    float m0 = blockRedN<1,4>(au), m1 = blockRedN<2,4>(au);
    float m2 = blockRedN<1,4>(av), m3 = blockRedN<2,4>(av);
    float m4 = blockRedN<1,4>(at), m5 = blockRedN<2,4>(at);
    if (!threadIdx.x){
      float* pp = pduv + blockIdx.x * 4;
      pp[0] = m0; pp[1] = m1; pp[2] = m2; pp[3] = m3;
      pdt[blockIdx.x * 2] = m4; pdt[blockIdx.x * 2 + 1] = m5;
    }
  }
  if (STAGE < 4){
    float Fti = (STAGE == 1) ? Ti : Ft[i];
    Uo[i] = Fui + cnext * ku;
    Vo[i] = Fvi + cnext * kv;
    To[i] = Fti + cnext * kt;
  }

  if (STAGE == 2){
    float qtv = -Fui * d_xf(Fq, rb, w, invpx) - Fvi * d_yf(Fq, bvbase, h, w) - wvi * d_zf(Fq, bbase, v, hw)
              + KHc * (dxxf(Fq, rb, w, invpx) + dyyf(Fq, bvbase, h, w)) + KVc * dzzf(Fq, bbase, v, hw) - prr[i];
    qtA[i] = qtv;
    float m0 = blockRedN<1,4>(qtv), m1 = blockRedN<2,4>(qtv);
    if (!threadIdx.x){ pqt[blockIdx.x * 2] = m0; pqt[blockIdx.x * 2 + 1] = m1; }
  }
}

__global__ void __launch_bounds__(64) zt_k(const float* __restrict__ k4t, float* __restrict__ zt, float* __restrict__ pmm)
{
  int col = blockIdx.x * 64 + threadIdx.x;
  int b = col >> 11, p = col & 2047;
  int fb = b * 13 * 2048 + p;
  float cum = 0.f, mn = FBIG, mx = -FBIG;
  #pragma unroll
  for (int v = 0; v < 13; ++v){
    cum += cDZ[v] * (-R_GASc / cPRS[v]) * k4t[fb + v * 2048];
    zt[fb + v * 2048] = cum;
    mn = fminf(mn, cum); mx = fmaxf(mx, cum);
  }
  mn = waveRedMin(mn); mx = waveRedMax(mx);
  if (!threadIdx.x){ pmm[blockIdx.x * 2] = mn; pmm[blockIdx.x * 2 + 1] = mx; }
}

// ===== fused: redundant sc2 finalize + outmid (LDS tile) + bf16 transpose out =====
__global__ void __launch_bounds__(256) outmid_fused_k(
  const float* __restrict__ hb,
  const float* __restrict__ Fz, const float* __restrict__ Fq, const float* __restrict__ Fu,
  const float* __restrict__ Fvf, const float* __restrict__ Ft,
  const float* __restrict__ ztA, const float* __restrict__ qtA,
  const float* __restrict__ duA, const float* __restrict__ dvA, const float* __restrict__ dtA,
  const float* __restrict__ coef, const float* __restrict__ partS,
  const float* __restrict__ pduv, const float* __restrict__ pdt,
  const float* __restrict__ pqt, const float* __restrict__ pzt,
  unsigned short* __restrict__ MT)
{
  __shared__ float tileBig[65 * 66];
  int blk = blockIdx.x, t = threadIdx.x;

  float fmn[5] = {FBIG, FBIG, FBIG, FBIG, FBIG};
  float fmx[5] = {-FBIG, -FBIG, -FBIG, -FBIG, -FBIG};
  float fsm[5] = {0.f, 0.f, 0.f, 0.f, 0.f};
  #pragma unroll 1
  for (int r0 = t; r0 < 384; r0 += 256){
    const float* pr = partS + r0 * 17;
    #pragma unroll
    for (int f = 0; f < 5; ++f){
      fmn[f] = fminf(fmn[f], pr[2 + f * 3]);
      fmx[f] = fmaxf(fmx[f], pr[3 + f * 3]);
      fsm[f] += pr[4 + f * 3];
    }
  }
  #pragma unroll
  for (int f = 0; f < 5; ++f){
    fmn[f] = blockRedN<1,4>(fmn[f]);
    fmx[f] = blockRedN<2,4>(fmx[f]);
    fsm[f] = blockRedN<0,4>(fsm[f]);
  }
  float dumn = FBIG, dumx = -FBIG, dvmn = FBIG, dvmx = -FBIG, dtmn = FBIG, dtmx = -FBIG;
  float qmn = FBIG, qmx = -FBIG;
  #pragma unroll 1
  for (int r0 = t; r0 < 832; r0 += 256){
    dumn = fminf(dumn, pduv[r0 * 4]);     dumx = fmaxf(dumx, pduv[r0 * 4 + 1]);
    dvmn = fminf(dvmn, pduv[r0 * 4 + 2]); dvmx = fmaxf(dvmx, pduv[r0 * 4 + 3]);
    dtmn = fminf(dtmn, pdt[r0 * 2]);      dtmx = fmaxf(dtmx, pdt[r0 * 2 + 1]);
    qmn = fminf(qmn, pqt[r0 * 2]);        qmx = fmaxf(qmx, pqt[r0 * 2 + 1]);
  }
  float zmn = pzt[t * 2], zmx = pzt[t * 2 + 1];
  dumn = blockRedN<1,4>(dumn); dumx = blockRedN<2,4>(dumx);
  dvmn = blockRedN<1,4>(dvmn); dvmx = blockRedN<2,4>(dvmx);
  dtmn = blockRedN<1,4>(dtmn); dtmx = blockRedN<2,4>(dtmx);
  qmn = blockRedN<1,4>(qmn);   qmx = blockRedN<2,4>(qmx);
  zmn = blockRedN<1,4>(zmn);   zmx = blockRedN<2,4>(zmx);

  float scf[5], off2[5];
  {
    float rmn[5] = {zmn, qmn, dumn, dvmn, dtmn};
    float rmx[5] = {zmx, qmx, dumx, dvmx, dtmx};
    float cfs[5] = {DT, DT, DT / 6.f, DT / 6.f, DT / 6.f};
    #pragma unroll
    for (int f = 0; f < 5; ++f){
      float mnf = fmn[f], mef = fsm[f] * (1.0f / (float)NF), mxf = fmx[f];
      float aa = (mnf - mef) * 0.05f, b2 = (mxf - mef) * 0.05f;
      float cf = cfs[f];
      float dmn = rmn[f] * cf, dmx = rmx[f] * cf;
      float s = (b2 - aa) / (dmx - dmn);
      scf[f] = s * cf; off2[f] = aa - dmn * s;
    }
  }

  int b = blk >> 5, h = blk & 31;
  #pragma unroll 1
  for (int idx = t; idx < 65 * 64; idx += 256){
    int c = idx >> 6, w = idx & 63;
    int f = c / 13, v = c - f * 13;
    int fi = (b * 13 + v) * 2048 + h * 64 + w;
    const float *Fp, *Rp;
    switch (f){
      case 0: Fp = Fz;  Rp = ztA; break;
      case 1: Fp = Fq;  Rp = qtA; break;
      case 2: Fp = Fu;  Rp = duA; break;
      case 3: Fp = Fvf; Rp = dvA; break;
      default: Fp = Ft; Rp = dtA; break;
    }
    float phys = Fp[fi] + Rp[fi] * scf[f] + off2[f];
    float cf = coef[c * 2048 + h * 64 + w];
    float hbv = hb[((size_t)(b * 65 + c)) * 2048 + h * 64 + w];
    tileBig[c * 66 + w] = cf * phys + (1.0f - cf) * hbv;
  }
  __syncthreads();
  #pragma unroll 1
  for (int ph = 0; ph < 6; ++ph){
    int cbase = ph * 16;
    int w = t >> 2, c4 = (t & 3) * 4;
    int c0 = cbase + c4;
    ushort4 o;
    o.x = (c0 + 0 < 65) ? f2bf(tileBig[(c0 + 0) * 66 + w]) : (unsigned short)0;
    o.y = (c0 + 1 < 65) ? f2bf(tileBig[(c0 + 1) * 66 + w]) : (unsigned short)0;
    o.z = (c0 + 2 < 65) ? f2bf(tileBig[(c0 + 2) * 66 + w]) : (unsigned short)0;
    o.w = (c0 + 3 < 65) ? f2bf(tileBig[(c0 + 3) * 66 + w]) : (unsigned short)0;
    *(ushort4*)(MT + (((size_t)(b * 32 + h) * 64 + w) * 96 + c0)) = o;
  }
}

// ===== final: redundant BN2 finalize + apply BN + residual =====
__global__ void __launch_bounds__(256) final_k(float* __restrict__ y, const float* __restrict__ x,
  const float* __restrict__ bnp2, const float* __restrict__ gblk, const float* __restrict__ bblk)
{
  int blk = blockIdx.x, t = threadIdx.x;
  int c = (blk >> 1) & 255;
  float4 pv = ((const float4*)(bnp2 + (size_t)c * 1024))[t];
  float s = pv.x + pv.z, sq = pv.y + pv.w;
  s = blockRedN<0,4>(s); sq = blockRedN<0,4>(sq);
  float m = s * (1.0f / 16384.0f);
  float var = sq * (1.0f / 16384.0f) - m * m;
  float rstd = rsqrtf(var + 1e-5f);
  float a = gblk[c] * rstd, bb = bblk[c] - m * gblk[c] * rstd;
  int e4 = blk * 256 + t;
  float4 v = ((const float4*)y)[e4];
  float4 xv = ((const float4*)x)[e4];
  v.x = v.x * a + bb + xv.x;
  v.y = v.y * a + bb + xv.y;
  v.z = v.z * a + bb + xv.z;
  v.w = v.w * a + bb + xv.w;
  ((float4*)y)[e4] = v;
}

extern "C" void kernel_launch(void* const* d_in, const int* in_sizes, int n_in,
                              void* d_out, int out_size, void* d_ws, size_t ws_size,
                              hipStream_t stream)
{
  (void)in_sizes; (void)n_in; (void)out_size; (void)ws_size;
  const float* x        = (const float*)d_in[0];
  const float* w_norm   = (const float*)d_in[1];
  const float* b_norm   = (const float*)d_in[2];
  const float* w_innorm = (const float*)d_in[3];
  const float* b_innorm = (const float*)d_in[4];
  const float* coef     = (const float*)d_in[5];
  GB gb;
  for (int f = 0; f < 5; ++f){
    gb.g[f] = (const float*)d_in[6 + 2 * f];
    gb.b[f] = (const float*)d_in[7 + 2 * f];
  }
  const float* gblk = (const float*)d_in[16];
  const float* bblk = (const float*)d_in[17];
  float* yout = (float*)d_out;

  float* ws = (float*)d_ws;
  size_t off = 0;
  auto alloc = [&](size_t n){ float* p = ws + off; off += n; return p; };
  float* hb  = alloc(NHB);
  float* Fz  = alloc(NF); float* Fq  = alloc(NF); float* Fu  = alloc(NF);
  float* Fvf = alloc(NF); float* Ft  = alloc(NF);
  float* zx  = alloc(NF); float* zy  = alloc(NF); float* zz  = alloc(NF);
  float* ux  = alloc(NF); float* vy  = alloc(NF); float* wvel = alloc(NF);
  float* C0  = alloc(NF); float* prr = alloc(NF);
  float* Ua  = alloc(NF); float* Ub  = alloc(NF); float* Va  = alloc(NF); float* Vb = alloc(NF);
  float* Ta  = alloc(NF); float* Tb  = alloc(NF);
  float* duA = alloc(NF); float* dvA = alloc(NF); float* dtA = alloc(NF);
  float* k4t = alloc(NF); float* ztA = alloc(NF); float* qtA = alloc(NF);
  float* part1 = alloc(384 * 17 + 4);       // 6532 (16B-align next)
  float* pduv = alloc(832 * 4); float* pdt = alloc(832 * 2);
  float* pqt  = alloc(832 * 2); float* pzt = alloc(256 * 2);
  float* bnp1 = alloc(65 * 512 * 2);        // [65][512][2]
  float* bnp2 = alloc(256 * 512 * 2);       // [256][512][2]
  float* Wp1f = alloc(9 * 80 * 256 / 2);    // bf16 [9][80][256]
  float* Wp2f = alloc(9 * 256 * 96 / 2);    // bf16 [9][256][96]
  unsigned short* Wp1 = (unsigned short*)Wp1f;
  unsigned short* Wp2 = (unsigned short*)Wp2f;
  // XT bf16 [8][32][64][256] (8 MB) aliases Ua..k4t (8.5 MB); dead after conv1,
  // long before stage1 writes Ua.
  unsigned short* XT = (unsigned short*)Ua;
  // MT bf16 [8][32][64][96] (3.15 MB) aliases C0,prr,Ua,Ub (3.4 MB) — dead after stage4;
  // outmid reads none of them.
  unsigned short* MT = (unsigned short*)C0;

  // 1. transpose x + pack both weights
  pre_k<<<2608, 256, 0, stream>>>(x, w_norm, w_innorm, XT, Wp1, Wp2);
  // 2. conv1 (bf16 MFMA, 32-pixel blocks, BN1 partials in epilogue)
  conv_mfma_k<256, 128, 65, 80, 5, 1, 7><<<dim3(64, 8), 5 * 64, 0, stream>>>(XT, Wp1, b_norm, hb, bnp1);
  // 3. prep (redundant BN1 finalize + 6-way field split + stat partials)
  prep_k<<<384, 256, 0, stream>>>(hb, bnp1, gb, Fz, Fq, Fu, Fvf, Ft, zx, zy, zz, ux, vy, wvel, part1);
  // 4-7. RK stages
  stage_k<1><<<NF / 256, 256, 0, stream>>>(Fu, Fvf, Ft, Fu, Fvf, Ft, Fq, ux, vy, zx, zy, wvel, zz, part1,
      C0, prr, Ua, Va, Ta, duA, dvA, dtA, k4t, qtA, pduv, pdt, pqt, 0.5f * DT);
  stage_k<2><<<NF / 256, 256, 0, stream>>>(Ua, Va, Ta, Fu, Fvf, Ft, Fq, ux, vy, zx, zy, wvel, zz, part1,
      C0, prr, Ub, Vb, Tb, duA, dvA, dtA, k4t, qtA, pduv, pdt, pqt, 0.5f * DT);
  stage_k<3><<<NF / 256, 256, 0, stream>>>(Ub, Vb, Tb, Fu, Fvf, Ft, Fq, ux, vy, zx, zy, wvel, zz, part1,
      C0, prr, Ua, Va, Ta, duA, dvA, dtA, k4t, qtA, pduv, pdt, pqt, DT);
  stage_k<4><<<NF / 256, 256, 0, stream>>>(Ua, Va, Ta, Fu, Fvf, Ft, Fq, ux, vy, zx, zy, wvel, zz, part1,
      C0, prr, Ub, Vb, Tb, duA, dvA, dtA, k4t, qtA, pduv, pdt, pqt, 0.f);
  // 8. z-tendency integral
  zt_k<<<256, 64, 0, stream>>>(k4t, ztA, pzt);
  // 9. fused finalize + outmid + bf16 transpose
  outmid_fused_k<<<256, 256, 0, stream>>>(hb, Fz, Fq, Fu, Fvf, Ft, ztA, qtA, duA, dvA, dtA,
      coef, part1, pduv, pdt, pqt, pzt, MT);
  // 10. conv2 (BN2 partials in epilogue)
  conv_mfma_k<96, 96, 256, 256, 8, 2, 3><<<dim3(64, 8), 8 * 64, 0, stream>>>(MT, Wp2, b_innorm, yout, bnp2);
  // 11. redundant BN2 finalize + apply + residual
  final_k<<<4096, 256, 0, stream>>>(yout, x, bnp2, gblk, bblk);
}